// Round 15
// baseline (598.564 us; speedup 1.0000x reference)
//
#include <hip/hip_runtime.h>
#include <hip/hip_bf16.h>
#include <cstdint>

typedef unsigned short u16;
typedef unsigned int u32;
typedef __attribute__((ext_vector_type(8))) short bf16x8;
typedef __attribute__((ext_vector_type(4))) float f32x4;
typedef __attribute__((ext_vector_type(16))) float f32x16;
typedef __attribute__((ext_vector_type(4))) unsigned int u32x4;

#define HIDDEN 4096
#define NH 32
#define NKV 8
#define HD 128
#define QSZ 4096
#define KVSZ 1024
#define QKV_N 6144
#define SEQ 2048
#define NB 2
#define NTOK (NB*SEQ)
#define ATT_SCALE 0.08838834764831845f
#define LOG2E 1.4426950408889634f
#define LN_EPS 1e-5f
#define THRD 12.0f   // defer-max threshold (log2 domain)

__device__ __forceinline__ u16 f2bf(float f) {
  union { float f; u32 u; } a; a.f = f;
  u32 r = a.u + 0x7fffu + ((a.u >> 16) & 1u);
  return (u16)(r >> 16);
}
__device__ __forceinline__ float bf2f(u16 h) {
  union { u32 u; float f; } a; a.u = ((u32)h) << 16;
  return a.f;
}

__device__ __forceinline__ void gload_lds16(const void* g, void* l) {
  __builtin_amdgcn_global_load_lds(
      (const __attribute__((address_space(1))) void*)g,
      (__attribute__((address_space(3))) void*)l,
      16, 0, 0);
}

// ---------------- stage 0a: f32 -> bf16 flat convert (8 elems/thread) -------
__global__ __launch_bounds__(256)
void conv_f32_bf16(const float* __restrict__ in, u16* __restrict__ out, int n8) {
  int i = blockIdx.x * 256 + threadIdx.x;
  if (i >= n8) return;
  const float4* p = (const float4*)in + (size_t)i * 2;
  float4 v0 = p[0], v1 = p[1];
  u32x4 o;
  o.x = (u32)f2bf(v0.x) | ((u32)f2bf(v0.y) << 16);
  o.y = (u32)f2bf(v0.z) | ((u32)f2bf(v0.w) << 16);
  o.z = (u32)f2bf(v1.x) | ((u32)f2bf(v1.y) << 16);
  o.w = (u32)f2bf(v1.z) | ((u32)f2bf(v1.w) << 16);
  ((u32x4*)out)[i] = o;
}

// ---------------- stage 0b: f32 [R][C] -> bf16 [C][R] transpose -------------
__global__ __launch_bounds__(256)
void transp_f32_bf16(const float* __restrict__ in, u16* __restrict__ out, int R, int C) {
  __shared__ float tile[32][33];
  int c0 = blockIdx.x << 5, r0 = blockIdx.y << 5;
  int tx = threadIdx.x & 31, ty = threadIdx.x >> 5; // 32 x 8
  #pragma unroll
  for (int j = 0; j < 32; j += 8)
    tile[ty + j][tx] = in[(long)(r0 + ty + j) * C + c0 + tx];
  __syncthreads();
  #pragma unroll
  for (int j = 0; j < 32; j += 8)
    out[(long)(c0 + ty + j) * R + r0 + tx] = f2bf(tile[tx][ty + j]);
}

// ---------------- GEMM v10: BM=128 BN=256 BK=32; 2 blocks/CU ---------------
// bt6 schedule skeleton (3-buffer ring, counted vmcnt(3), ONE barrier/tile,
// setprio) at BK=32: buffer = 24KB (A 8KB + B 16KB), ring = 72KB -> TWO
// blocks/CU co-resident; barrier stalls of one block hidden by the other
// (m114 co-scheduling — the mechanism all >=128KB configs lacked).
// LDS layout: pair-interleaved 128B lines — line L holds rows 2L,2L+1;
// chunk(16B) logical = (row&1)*4 + kc (kc = k/8 in 0..3);
// phys = logical ^ (line&7). Staged via pre-inverse-swizzled global source:
// chunk ci -> line=ci>>3, phys=ci&7, logical=phys^(line&7),
// row=2*line+(logical>>2), kc=logical&3. Round-trip verified.
template<typename OutT>
__global__ __launch_bounds__(512, 4)
void gemm_bt9(const u16* __restrict__ A, const u16* __restrict__ Bt,
              OutT* __restrict__ C, int N, int K) {
  extern __shared__ char smem[];            // 3 * 24576 bytes
  const int t = threadIdx.x;
  const int lane = t & 63, w = t >> 6;
  const int wr = w >> 2, wc = w & 3;        // 2M x 4N waves, wave tile 64x64
  const int l31 = lane & 31, g2 = lane >> 5;
  const int bm = blockIdx.y, bn = blockIdx.x;

  // staging sources (one A chunk, two B chunks per thread)
  const u16* pA;  const u16* pB0;  const u16* pB1;
  {
    int ci = t;                               // A: 512 chunks (8KB)
    int line = ci >> 3, phys = ci & 7;
    int lg = phys ^ (line & 7);
    pA = A + (long)(bm * 128 + 2 * line + (lg >> 2)) * K + ((lg & 3) << 3);
    ci = t;                                   // B chunk 0
    line = ci >> 3; phys = ci & 7; lg = phys ^ (line & 7);
    pB0 = Bt + (long)(bn * 256 + 2 * line + (lg >> 2)) * K + ((lg & 3) << 3);
    ci = t + 512;                             // B chunk 1
    line = ci >> 3; phys = ci & 7; lg = phys ^ (line & 7);
    pB1 = Bt + (long)(bn * 256 + 2 * line + (lg >> 2)) * K + ((lg & 3) << 3);
  }
  const int dS = w * 1024;                    // wave-uniform dest (HW adds lane*16)

  // fragment read helpers: A line = wr*32 + i*16 + (l31>>1)  (region @0)
  //                        B line = wc*32 + j*16 + (l31>>1)  (region @8192)
  const int lhalf = l31 >> 1;
  const int lgbase = (l31 & 1) * 4 + g2;      // + s*2 -> logical chunk

  f32x16 acc[2][2];
  #pragma unroll
  for (int i = 0; i < 2; ++i)
    #pragma unroll
    for (int j = 0; j < 2; ++j)
      #pragma unroll
      for (int r = 0; r < 16; ++r) acc[i][j][r] = 0.f;

  const int nt = K >> 5;
  char* cbase = smem;
  char* nbase = smem + 24576;
  char* sbase = smem + 49152;

  #define STAGE9(dst, koff) { \
    gload_lds16(pA  + (koff), (dst) + dS); \
    gload_lds16(pB0 + (koff), (dst) + 8192 + dS); \
    gload_lds16(pB1 + (koff), (dst) + 16384 + dS); }

  // prologue: stage tiles 0 and 1; wait tile 0 only (3 newest stay in flight)
  STAGE9(cbase, 0);
  STAGE9(nbase, 32);
  asm volatile("s_waitcnt vmcnt(3)" ::: "memory");
  __builtin_amdgcn_s_barrier();
  __builtin_amdgcn_sched_barrier(0);

  // READ9(dst, s): dst[0..1] = A-frags i=0,1 ; dst[2..3] = B-frags j=0,1
  #define READ9(dst, s) { \
    const int lg_ = lgbase + (s) * 2; \
    { int ln_ = wr * 32 + lhalf;          int ph_ = lg_ ^ (ln_ & 7); \
      dst[0] = *(const bf16x8*)(cbase + ln_ * 128 + ph_ * 16); } \
    { int ln_ = wr * 32 + 16 + lhalf;     int ph_ = lg_ ^ (ln_ & 7); \
      dst[1] = *(const bf16x8*)(cbase + ln_ * 128 + ph_ * 16); } \
    { int ln_ = wc * 32 + lhalf;          int ph_ = lg_ ^ (ln_ & 7); \
      dst[2] = *(const bf16x8*)(cbase + 8192 + ln_ * 128 + ph_ * 16); } \
    { int ln_ = wc * 32 + 16 + lhalf;     int ph_ = lg_ ^ (ln_ & 7); \
      dst[3] = *(const bf16x8*)(cbase + 8192 + ln_ * 128 + ph_ * 16); } }
  #define MFMA9(f) { \
    __builtin_amdgcn_s_setprio(1); \
    acc[0][0] = __builtin_amdgcn_mfma_f32_32x32x16_bf16(f[0], f[2], acc[0][0], 0, 0, 0); \
    acc[0][1] = __builtin_amdgcn_mfma_f32_32x32x16_bf16(f[0], f[3], acc[0][1], 0, 0, 0); \
    acc[1][0] = __builtin_amdgcn_mfma_f32_32x32x16_bf16(f[1], f[2], acc[1][0], 0, 0, 0); \
    acc[1][1] = __builtin_amdgcn_mfma_f32_32x32x16_bf16(f[1], f[3], acc[1][1], 0, 0, 0); \
    __builtin_amdgcn_s_setprio(0); }

  for (int tt = 0; tt < nt; ++tt) {
    const long sk = (long)((tt + 2 < nt) ? (tt + 2) : (nt - 1)) * 32; // clamp keeps counts uniform
    bf16x8 f0[4], f1[4];
    READ9(f0, 0);
    READ9(f1, 1);
    STAGE9(sbase, sk);                 // tile t+2 into slot freed at t-1
    MFMA9(f0);
    MFMA9(f1);
    // tile t+1 landed (its 3 loads are oldest of 6 outstanding)
    asm volatile("s_waitcnt vmcnt(3)" ::: "memory");
    __builtin_amdgcn_s_barrier();
    __builtin_amdgcn_sched_barrier(0);
    char* tmp = cbase; cbase = nbase; nbase = sbase; sbase = tmp;
  }
  #undef READ9
  #undef MFMA9
  #undef STAGE9

  // epilogue: C/D layout col = lane&31, row = (r&3) + 8*(r>>2) + 4*(lane>>5)
  #pragma unroll
  for (int mf = 0; mf < 2; ++mf)
    #pragma unroll
    for (int nf = 0; nf < 2; ++nf)
      #pragma unroll
      for (int r = 0; r < 16; ++r) {
        long row = bm * 128 + wr * 64 + mf * 32 + (r & 3) + 8 * (r >> 2) + 4 * g2;
        long col = bn * 256 + wc * 64 + nf * 32 + l31;
        float v = acc[mf][nf][r];
        if constexpr (sizeof(OutT) == 2) C[row * N + col] = f2bf(v);
        else                             C[row * N + col] = v;
      }
}

// ---------------- stage 2: headwise LN + RoPE(GPT-J) + scale ----------------
__device__ __forceinline__ void ln_rope_head(const u16* __restrict__ src,
                                             const float* __restrict__ wgt,
                                             u16* __restrict__ dst,
                                             int lane, float sa, float ca, float scale) {
  u32 xr = *(const u32*)(src + 2 * lane);
  float x1 = bf2f((u16)(xr & 0xffffu)), x2 = bf2f((u16)(xr >> 16));
  float ssum = x1 + x2;
  #pragma unroll
  for (int off = 1; off < 64; off <<= 1) ssum += __shfl_xor(ssum, off);
  float mean = ssum * (1.0f / 128.0f);
  float e1 = x1 - mean, e2 = x2 - mean;
  float vv = e1 * e1 + e2 * e2;
  #pragma unroll
  for (int off = 1; off < 64; off <<= 1) vv += __shfl_xor(vv, off);
  float rstd = rsqrtf(vv * (1.0f / 128.0f) + LN_EPS);
  float y1 = e1 * rstd * wgt[2 * lane];
  float y2 = e2 * rstd * wgt[2 * lane + 1];
  float o1 = (y1 * ca - y2 * sa) * scale;
  float o2 = (y2 * ca + y1 * sa) * scale;
  *(u32*)(dst + 2 * lane) = (u32)f2bf(o1) | ((u32)f2bf(o2) << 16);
}

__global__ __launch_bounds__(512)
void ln_rope(const u16* __restrict__ qkv, const int* __restrict__ pos,
             const float* __restrict__ qw, const float* __restrict__ kw,
             u16* __restrict__ qo, u16* __restrict__ ko) {
  const int s = blockIdx.x, b = blockIdx.y;
  const int t = threadIdx.x, lane = t & 63, w = t >> 6; // 8 waves
  const long base = (long)(b * SEQ + s) * QKV_N;
  const int p = pos[b * SEQ + s];
  const float expo = (float)(2 * lane) * (1.0f / 128.0f);
  const float inv_freq = exp2f(-expo * 13.287712379549449f); // log2(10000)
  float sa, ca;
  sincosf((float)p * inv_freq, &sa, &ca);
  #pragma unroll
  for (int hh = 0; hh < 4; ++hh) {
    int h = w + hh * 8;
    ln_rope_head(qkv + base + h * HD, qw + h * HD,
                 qo + (((long)b * NH + h) * SEQ + s) * HD, lane, sa, ca,
                 ATT_SCALE * LOG2E);  // fold log2e: flash uses exp2
  }
  ln_rope_head(qkv + base + QSZ + w * HD, kw + w * HD,
               ko + (((long)b * NKV + w) * SEQ + s) * HD, lane, sa, ca, 1.0f);
}

// ---------------- stage 2b: V slice of qkv -> V^T [b][kvh][d][S] ------------
__global__ __launch_bounds__(256)
void v_transp(const u16* __restrict__ qkv, u16* __restrict__ vt) {
  __shared__ u16 tile[32][33];
  int s0 = blockIdx.x * 32, d0 = blockIdx.y * 32;
  int bk = blockIdx.z;                 // b*NKV + kvh
  int b = bk >> 3, kvh = bk & 7;
  int tx = threadIdx.x & 31, ty = threadIdx.x >> 5;
  const u16* src = qkv + ((long)(b * SEQ) + s0) * QKV_N + QSZ + KVSZ + kvh * HD + d0;
  #pragma unroll
  for (int j = 0; j < 32; j += 8)
    tile[ty + j][tx] = src[(long)(ty + j) * QKV_N + tx];
  __syncthreads();
  u16* dst = vt + (((long)bk) * HD + d0) * SEQ + s0;
  #pragma unroll
  for (int j = 0; j < 32; j += 8)
    dst[(long)(ty + j) * SEQ + tx] = tile[tx][ty + j];
}

// ---------------- stage 3: balanced causal GQA flash attention --------------
// 256 blocks (1/CU) x 512 thr; block (b,h,qp) processes q-tiles {7-qp, qp}:
// causal work = 36 KV-tiles/block, perfectly balanced.
__global__ __launch_bounds__(512, 2)
void flash_attn3(const u16* __restrict__ Qg, const u16* __restrict__ Kg,
                 const u16* __restrict__ Vtg, u16* __restrict__ Og) {
  const int lin = blockIdx.x;          // 256 blocks
  const int b = lin >> 7;
  const int rem = lin & 127;
  const int h = rem >> 2;
  const int qp = rem & 3;
  const int kvh = h >> 2;
  const int t = threadIdx.x, lane = t & 63, w = t >> 6;
  const int hh = lane >> 5, l31 = lane & 31;

  __shared__ u16 Klds[2][64 * 128];   // 2 x 16KB
  __shared__ u16 Vlds[2][128 * 64];   // 2 x 16KB

  const u16* Kbase = Kg + ((long)b * NKV + kvh) * (long)SEQ * HD;   // [kv][128]
  const u16* Vtbase = Vtg + ((long)b * NKV + kvh) * (long)HD * SEQ; // [d][2048]

  auto STAGE = [&](int buf, int kt) {
    const int kv0 = kt * 64;
    #pragma unroll
    for (int i = 0; i < 2; ++i) {   // K: 1024 chunks of 16B
      int c = t + i * 512;
      int kv = c >> 4, cc = c & 15;
      int cl = (cc & 8) | ((cc ^ kv) & 7);      // inverse swizzle on source
      gload_lds16(Kbase + (long)(kv0 + kv) * HD + cl * 8,
                  (char*)(&Klds[buf][0]) + (i * 512 + w * 64) * 16);
    }
    #pragma unroll
    for (int i = 0; i < 2; ++i) {   // V^T: 1024 chunks of 16B
      int c = t + i * 512;
      int d = c >> 3, cc = c & 7;
      int cl = cc ^ (d & 7);
      gload_lds16(Vtbase + (long)d * SEQ + kv0 + cl * 8,
                  (char*)(&Vlds[buf][0]) + (i * 512 + w * 64) * 16);
    }
  };

  for (int seg = 0; seg < 2; ++seg) {
    const int qt = seg ? qp : (7 - qp);   // heavy first
    const int wq0 = qt * 256 + w * 32;
    const int q = wq0 + l31;
    const u16* Qbase = Qg + (((long)b * NH + h) * SEQ + q) * HD + hh * 8;
    bf16x8 qf[8];
    #pragma unroll
    for (int ks = 0; ks < 8; ++ks) qf[ks] = *(const bf16x8*)(Qbase + ks * 16);

    f32x16 o[4];
    #pragma unroll
    for (int i = 0; i < 4; ++i)
      #pragma unroll
      for (int r = 0; r < 16; ++r) o[i][r] = 0.f;
    float m = -1e30f, l = 0.f;
    const int nt = qt * 4 + 4;

    __syncthreads();                 // seg1: all waves done reading seg0's LDS
    STAGE(0, 0);
    __syncthreads();
    int cur = 0;
    for (int kt = 0; kt < nt; ++kt) {
      const int kv0 = kt * 64;
      if (kt + 1 < nt) STAGE(cur ^ 1, kt + 1);
      if (kv0 <= wq0 + 31) {
        const char* Kb = (const char*)(&Klds[cur][0]);
        const char* Vb = (const char*)(&Vlds[cur][0]);
        f32x16 st[2];
        #pragma unroll
        for (int tt = 0; tt < 2; ++tt)
          #pragma unroll
          for (int r = 0; r < 16; ++r) st[tt][r] = 0.f;
        __builtin_amdgcn_s_setprio(1);
        #pragma unroll
        for (int tt = 0; tt < 2; ++tt) {
          if (kv0 + tt * 32 <= wq0 + 31) {
            #pragma unroll
            for (int ks = 0; ks < 8; ++ks) {
              int ch = ks * 2 + hh;
              int pc = (ch & 8) | ((ch ^ l31) & 7);   // swizzled read
              bf16x8 kf = *(const bf16x8*)(Kb + (tt * 32 + l31) * 256 + pc * 16);
              st[tt] = __builtin_amdgcn_mfma_f32_32x32x16_bf16(kf, qf[ks], st[tt], 0, 0, 0);
            }
          }
        }
        __builtin_amdgcn_s_setprio(0);
        if (kv0 + 63 > wq0) {
          #pragma unroll
          for (int tt = 0; tt < 2; ++tt)
            #pragma unroll
            for (int r = 0; r < 16; ++r) {
              int kva = kv0 + tt * 32 + (r & 3) + 8 * (r >> 2) + 4 * hh;
              if (kva > q) st[tt][r] = -1e30f;
            }
        }
        float p0 = -1e30f, p1 = -1e30f, p2 = -1e30f, p3 = -1e30f;
        #pragma unroll
        for (int tt = 0; tt < 2; ++tt)
          #pragma unroll
          for (int r = 0; r < 16; r += 4) {
            p0 = fmaxf(p0, st[tt][r]);
            p1 = fmaxf(p1, st[tt][r + 1]);
            p2 = fmaxf(p2, st[tt][r + 2]);
            p3 = fmaxf(p3, st[tt][r + 3]);
          }
        float mx = fmaxf(fmaxf(p0, p1), fmaxf(p2, p3));
        mx = fmaxf(mx, __shfl_xor(mx, 32));
        if (!__all(mx - m <= THRD)) {            // defer-max (T13)
          float mn = fmaxf(m, mx);
          float sc = exp2f(m - mn);
          m = mn;
          float scr[16];
          #pragma unroll
          for (int r = 0; r < 16; ++r)
            scr[r] = __shfl(sc, (r & 3) + 8 * (r >> 2) + 4 * hh);
          #pragma unroll
          for (int db = 0; db < 4; ++db)
            #pragma unroll
            for (int r = 0; r < 16; ++r) o[db][r] *= scr[r];
          l *= sc;
        }
        float s0 = 0.f, s1 = 0.f, s2 = 0.f, s3 = 0.f;
        #pragma unroll
        for (int tt = 0; tt < 2; ++tt)
          #pragma unroll
          for (int r = 0; r < 16; r += 4) {
            float e0 = exp2f(st[tt][r] - m);
            float e1 = exp2f(st[tt][r + 1] - m);
            float e2 = exp2f(st[tt][r + 2] - m);
            float e3 = exp2f(st[tt][r + 3] - m);
            st[tt][r] = e0; st[tt][r + 1] = e1; st[tt][r + 2] = e2; st[tt][r + 3] = e3;
            s0 += e0; s1 += e1; s2 += e2; s3 += e3;
          }
        float rs = (s0 + s1) + (s2 + s3);
        rs += __shfl_xor(rs, 32);
        l += rs;
        bf16x8 pa[4];
        #pragma unroll
        for (int k4 = 0; k4 < 4; ++k4) {
          int s8 = (k4 & 1) * 8, tt = k4 >> 1;
          u32 x0 = (u32)f2bf(st[tt][s8 + 0]) | ((u32)f2bf(st[tt][s8 + 1]) << 16);
          u32 x1 = (u32)f2bf(st[tt][s8 + 2]) | ((u32)f2bf(st[tt][s8 + 3]) << 16);
          u32 y0 = (u32)f2bf(st[tt][s8 + 4]) | ((u32)f2bf(st[tt][s8 + 5]) << 16);
          u32 y1 = (u32)f2bf(st[tt][s8 + 6]) | ((u32)f2bf(st[tt][s8 + 7]) << 16);
          u32 x0s = (u32)__shfl_xor((int)x0, 32), x1s = (u32)__shfl_xor((int)x1, 32);
          u32 y0s = (u32)__shfl_xor((int)y0, 32), y1s = (u32)__shfl_xor((int)y1, 32);
          union { u32 u[4]; bf16x8 v; } pk;
          pk.u[0] = hh ? y0s : x0;
          pk.u[1] = hh ? y1s : x1;
          pk.u[2] = hh ? y0 : x0s;
          pk.u[3] = hh ? y1 : x1s;
          pa[k4] = pk.v;
        }
        __builtin_amdgcn_s_setprio(1);
        #pragma unroll
        for (int k4 = 0; k4 < 4; ++k4)
          #pragma unroll
          for (int db = 0; db < 4; ++db) {
            int ch = k4 * 2 + hh;
            int pcc = ch ^ (l31 & 7);
            bf16x8 vf = *(const bf16x8*)(Vb + (db * 32 + l31) * 128 + pcc * 16);
            o[db] = __builtin_amdgcn_mfma_f32_32x32x16_bf16(pa[k4], vf, o[db], 0, 0, 0);
          }
        __builtin_amdgcn_s_setprio(0);
      }
      __syncthreads();
      cur ^= 1;
    }
    float linv = 1.0f / l;
    float li[16];
    #pragma unroll
    for (int r = 0; r < 16; ++r)
      li[r] = __shfl(linv, (r & 3) + 8 * (r >> 2) + 4 * hh);
    #pragma unroll
    for (int db = 0; db < 4; ++db)
      #pragma unroll
      for (int r = 0; r < 16; ++r) {
        int qr = wq0 + (r & 3) + 8 * (r >> 2) + 4 * hh;
        Og[((long)b * SEQ + qr) * QSZ + h * HD + db * 32 + l31] = f2bf(o[db][r] * li[r]);
      }
  }
}

// ---------------- launch -----------------------------------------------------
extern "C" void kernel_launch(void* const* d_in, const int* in_sizes, int n_in,
                              void* d_out, int out_size, void* d_ws, size_t ws_size,
                              hipStream_t stream) {
  const int*   positions = (const int*)d_in[0];
  const float* hidden    = (const float*)d_in[1];
  const float* Wqkv      = (const float*)d_in[2];
  const float* qnw       = (const float*)d_in[3];
  const float* knw       = (const float*)d_in[4];
  const float* Wo        = (const float*)d_in[5];
  float* out = (float*)d_out;
  char* ws = (char*)d_ws;
  const size_t MB = 1024 * 1024;
  u16* hbf   = (u16*)(ws + 0);        // 32MB: hidden bf16 (dead after gemm1)
  u16* WqkvT = (u16*)(ws + 32 * MB);  // 48MB: Wqkv^T bf16 (dead after gemm1)
  u16* qkvb  = (u16*)(ws + 80 * MB);  // 48MB: qkv bf16 (dead after ln_rope+v_transp)
  u16* q_arr = (u16*)(ws + 0);        // 32MB (aliases hbf)
  u16* k_arr = (u16*)(ws + 32 * MB);  //  8MB (aliases WqkvT[0:8M])
  u16* vt_arr= (u16*)(ws + 40 * MB);  //  8MB V^T [b][kvh][d][S]
  u16* WoT   = (u16*)(ws + 48 * MB);  // 32MB (aliases WqkvT[16M:48M])
  u16* Oarr  = (u16*)(ws + 80 * MB);  // 32MB (aliases qkvb[0:32M])

  const int GEMM_LDS = 3 * 24576;     // 72 KB -> 2 blocks/CU
  (void)hipFuncSetAttribute((const void*)&gemm_bt9<u16>,
        hipFuncAttributeMaxDynamicSharedMemorySize, GEMM_LDS);
  (void)hipFuncSetAttribute((const void*)&gemm_bt9<float>,
        hipFuncAttributeMaxDynamicSharedMemorySize, GEMM_LDS);

  conv_f32_bf16<<<dim3(NTOK * HIDDEN / 8 / 256), 256, 0, stream>>>(hidden, hbf, NTOK * HIDDEN / 8);
  transp_f32_bf16<<<dim3(QKV_N / 32, HIDDEN / 32), 256, 0, stream>>>(Wqkv, WqkvT, HIDDEN, QKV_N);
  gemm_bt9<u16><<<dim3(QKV_N / 256, NTOK / 128), 512, GEMM_LDS, stream>>>(hbf, WqkvT, qkvb, QKV_N, HIDDEN);
  ln_rope<<<dim3(SEQ, NB), 512, 0, stream>>>(qkvb, positions, qnw, knw, q_arr, k_arr);
  v_transp<<<dim3(SEQ / 32, HD / 32, NB * NKV), 256, 0, stream>>>(qkvb, vt_arr);
  transp_f32_bf16<<<dim3(HIDDEN / 32, QSZ / 32), 256, 0, stream>>>(Wo, WoT, QSZ, HIDDEN);
  flash_attn3<<<dim3(256), 512, 0, stream>>>(q_arr, k_arr, vt_arr, Oarr);
  gemm_bt9<float><<<dim3(HIDDEN / 256, NTOK / 128), 512, GEMM_LDS, stream>>>(Oarr, WoT, out, HIDDEN, QSZ);
}

// Round 16
// 578.464 us; speedup vs baseline: 1.0347x; 1.0347x over previous
//
#include <hip/hip_runtime.h>
#include <hip/hip_bf16.h>
#include <cstdint>

typedef unsigned short u16;
typedef unsigned int u32;
typedef __attribute__((ext_vector_type(8))) short bf16x8;
typedef __attribute__((ext_vector_type(4))) float f32x4;
typedef __attribute__((ext_vector_type(16))) float f32x16;
typedef __attribute__((ext_vector_type(4))) unsigned int u32x4;

#define HIDDEN 4096
#define NH 32
#define NKV 8
#define HD 128
#define QSZ 4096
#define KVSZ 1024
#define QKV_N 6144
#define SEQ 2048
#define NB 2
#define NTOK (NB*SEQ)
#define ATT_SCALE 0.08838834764831845f
#define LOG2E 1.4426950408889634f
#define LN_EPS 1e-5f
#define THRD 12.0f   // defer-max threshold (log2 domain)

__device__ __forceinline__ u16 f2bf(float f) {
  union { float f; u32 u; } a; a.f = f;
  u32 r = a.u + 0x7fffu + ((a.u >> 16) & 1u);
  return (u16)(r >> 16);
}
__device__ __forceinline__ float bf2f(u16 h) {
  union { u32 u; float f; } a; a.u = ((u32)h) << 16;
  return a.f;
}

__device__ __forceinline__ void gload_lds16(const void* g, void* l) {
  __builtin_amdgcn_global_load_lds(
      (const __attribute__((address_space(1))) void*)g,
      (__attribute__((address_space(3))) void*)l,
      16, 0, 0);
}

// ---------------- stage 0a: f32 -> bf16 flat convert (8 elems/thread) -------
__global__ __launch_bounds__(256)
void conv_f32_bf16(const float* __restrict__ in, u16* __restrict__ out, int n8) {
  int i = blockIdx.x * 256 + threadIdx.x;
  if (i >= n8) return;
  const float4* p = (const float4*)in + (size_t)i * 2;
  float4 v0 = p[0], v1 = p[1];
  u32x4 o;
  o.x = (u32)f2bf(v0.x) | ((u32)f2bf(v0.y) << 16);
  o.y = (u32)f2bf(v0.z) | ((u32)f2bf(v0.w) << 16);
  o.z = (u32)f2bf(v1.x) | ((u32)f2bf(v1.y) << 16);
  o.w = (u32)f2bf(v1.z) | ((u32)f2bf(v1.w) << 16);
  ((u32x4*)out)[i] = o;
}

// ---------------- stage 0b: f32 [R][C] -> bf16 [C][R] transpose -------------
__global__ __launch_bounds__(256)
void transp_f32_bf16(const float* __restrict__ in, u16* __restrict__ out, int R, int C) {
  __shared__ float tile[32][33];
  int c0 = blockIdx.x << 5, r0 = blockIdx.y << 5;
  int tx = threadIdx.x & 31, ty = threadIdx.x >> 5; // 32 x 8
  #pragma unroll
  for (int j = 0; j < 32; j += 8)
    tile[ty + j][tx] = in[(long)(r0 + ty + j) * C + c0 + tx];
  __syncthreads();
  #pragma unroll
  for (int j = 0; j < 32; j += 8)
    out[(long)(c0 + ty + j) * R + r0 + tx] = f2bf(tile[tx][ty + j]);
}

// ---------------- GEMM QKV (r15-measured best, 229.5us): BK=32, 2 blk/CU ----
// 3-buffer ring (3x24KB=72KB), counted vmcnt(3), ONE barrier/tile, setprio.
// Pair-interleaved 128B lines; phys = logical ^ (line&7), pre-swizzled source.
template<typename OutT>
__global__ __launch_bounds__(512, 4)
void gemm_bt9(const u16* __restrict__ A, const u16* __restrict__ Bt,
              OutT* __restrict__ C, int N, int K) {
  extern __shared__ char smem[];            // 3 * 24576 bytes
  const int t = threadIdx.x;
  const int lane = t & 63, w = t >> 6;
  const int wr = w >> 2, wc = w & 3;        // 2M x 4N waves, wave tile 64x64
  const int l31 = lane & 31, g2 = lane >> 5;
  const int bm = blockIdx.y, bn = blockIdx.x;

  const u16* pA;  const u16* pB0;  const u16* pB1;
  {
    int ci = t;                               // A: 512 chunks (8KB)
    int line = ci >> 3, phys = ci & 7;
    int lg = phys ^ (line & 7);
    pA = A + (long)(bm * 128 + 2 * line + (lg >> 2)) * K + ((lg & 3) << 3);
    ci = t;                                   // B chunk 0
    line = ci >> 3; phys = ci & 7; lg = phys ^ (line & 7);
    pB0 = Bt + (long)(bn * 256 + 2 * line + (lg >> 2)) * K + ((lg & 3) << 3);
    ci = t + 512;                             // B chunk 1
    line = ci >> 3; phys = ci & 7; lg = phys ^ (line & 7);
    pB1 = Bt + (long)(bn * 256 + 2 * line + (lg >> 2)) * K + ((lg & 3) << 3);
  }
  const int dS = w * 1024;                    // wave-uniform dest (HW adds lane*16)

  const int lhalf = l31 >> 1;
  const int lgbase = (l31 & 1) * 4 + g2;      // + s*2 -> logical chunk

  f32x16 acc[2][2];
  #pragma unroll
  for (int i = 0; i < 2; ++i)
    #pragma unroll
    for (int j = 0; j < 2; ++j)
      #pragma unroll
      for (int r = 0; r < 16; ++r) acc[i][j][r] = 0.f;

  const int nt = K >> 5;
  char* cbase = smem;
  char* nbase = smem + 24576;
  char* sbase = smem + 49152;

  #define STAGE9(dst, koff) { \
    gload_lds16(pA  + (koff), (dst) + dS); \
    gload_lds16(pB0 + (koff), (dst) + 8192 + dS); \
    gload_lds16(pB1 + (koff), (dst) + 16384 + dS); }

  STAGE9(cbase, 0);
  STAGE9(nbase, 32);
  asm volatile("s_waitcnt vmcnt(3)" ::: "memory");
  __builtin_amdgcn_s_barrier();
  __builtin_amdgcn_sched_barrier(0);

  #define READ9(dst, s) { \
    const int lg_ = lgbase + (s) * 2; \
    { int ln_ = wr * 32 + lhalf;          int ph_ = lg_ ^ (ln_ & 7); \
      dst[0] = *(const bf16x8*)(cbase + ln_ * 128 + ph_ * 16); } \
    { int ln_ = wr * 32 + 16 + lhalf;     int ph_ = lg_ ^ (ln_ & 7); \
      dst[1] = *(const bf16x8*)(cbase + ln_ * 128 + ph_ * 16); } \
    { int ln_ = wc * 32 + lhalf;          int ph_ = lg_ ^ (ln_ & 7); \
      dst[2] = *(const bf16x8*)(cbase + 8192 + ln_ * 128 + ph_ * 16); } \
    { int ln_ = wc * 32 + 16 + lhalf;     int ph_ = lg_ ^ (ln_ & 7); \
      dst[3] = *(const bf16x8*)(cbase + 8192 + ln_ * 128 + ph_ * 16); } }
  #define MFMA9(f) { \
    __builtin_amdgcn_s_setprio(1); \
    acc[0][0] = __builtin_amdgcn_mfma_f32_32x32x16_bf16(f[0], f[2], acc[0][0], 0, 0, 0); \
    acc[0][1] = __builtin_amdgcn_mfma_f32_32x32x16_bf16(f[0], f[3], acc[0][1], 0, 0, 0); \
    acc[1][0] = __builtin_amdgcn_mfma_f32_32x32x16_bf16(f[1], f[2], acc[1][0], 0, 0, 0); \
    acc[1][1] = __builtin_amdgcn_mfma_f32_32x32x16_bf16(f[1], f[3], acc[1][1], 0, 0, 0); \
    __builtin_amdgcn_s_setprio(0); }

  for (int tt = 0; tt < nt; ++tt) {
    const long sk = (long)((tt + 2 < nt) ? (tt + 2) : (nt - 1)) * 32;
    bf16x8 f0[4], f1[4];
    READ9(f0, 0);
    READ9(f1, 1);
    STAGE9(sbase, sk);
    MFMA9(f0);
    MFMA9(f1);
    asm volatile("s_waitcnt vmcnt(3)" ::: "memory");
    __builtin_amdgcn_s_barrier();
    __builtin_amdgcn_sched_barrier(0);
    char* tmp = cbase; cbase = nbase; nbase = sbase; sbase = tmp;
  }
  #undef READ9
  #undef MFMA9
  #undef STAGE9

  #pragma unroll
  for (int mf = 0; mf < 2; ++mf)
    #pragma unroll
    for (int nf = 0; nf < 2; ++nf)
      #pragma unroll
      for (int r = 0; r < 16; ++r) {
        long row = bm * 128 + wr * 64 + mf * 32 + (r & 3) + 8 * (r >> 2) + 4 * g2;
        long col = bn * 256 + wc * 64 + nf * 32 + l31;
        float v = acc[mf][nf][r];
        if constexpr (sizeof(OutT) == 2) C[row * N + col] = f2bf(v);
        else                             C[row * N + col] = v;
      }
}

// ---------------- GEMM out (r6/r14-measured best): BM=BN=256 BK=64 ----------
// 8 waves (2M x 4N), wave-tile 128x64; 2-buffer LDS (128KB); stage loads
// interleaved mid-tile; one vmcnt(0)+barrier per K-tile. 8-chunk XOR swizzle.
template<typename OutT>
__global__ __launch_bounds__(512, 2)
void gemm_bt4(const u16* __restrict__ A, const u16* __restrict__ Bt,
              OutT* __restrict__ C, int N, int K) {
  extern __shared__ char smem[];            // 2 * 65536 bytes
  const int t = threadIdx.x;
  const int lane = t & 63, w = t >> 6;
  const int wr = w >> 2, wc = w & 3;
  const int l31 = lane & 31, g2 = lane >> 5;
  const int bm = blockIdx.y, bn = blockIdx.x;

  const u16* pA[4]; const u16* pB[4];
  int dS[4];
  #pragma unroll
  for (int i = 0; i < 4; ++i) {
    int ci = t + i * 512;
    int row = ci >> 3;
    int c = (ci & 7) ^ (row & 7);
    pA[i] = A  + (long)(bm * 256 + row) * K + (c << 3);
    pB[i] = Bt + (long)(bn * 256 + row) * K + (c << 3);
    dS[i] = (i * 512 + w * 64) * 16;
  }

  const int arowB = (wr * 128 + l31) * 128;
  const int browB = 32768 + (wc * 64 + l31) * 128;

  f32x16 acc[4][2];
  #pragma unroll
  for (int i = 0; i < 4; ++i)
    #pragma unroll
    for (int j = 0; j < 2; ++j)
      #pragma unroll
      for (int r = 0; r < 16; ++r) acc[i][j][r] = 0.f;

  const int nt = K >> 6;
  char* cb = smem;
  char* sb = smem + 65536;

  #pragma unroll
  for (int i = 0; i < 4; ++i) gload_lds16(pA[i], cb + dS[i]);
  #pragma unroll
  for (int i = 0; i < 4; ++i) gload_lds16(pB[i], cb + 32768 + dS[i]);
  asm volatile("s_waitcnt vmcnt(0)" ::: "memory");
  __builtin_amdgcn_s_barrier();
  __builtin_amdgcn_sched_barrier(0);

  #define READ_KK4(dst, kkv) { \
    const int pcb = ((((kkv) * 2 + g2)) ^ (l31 & 7)) << 4; \
    dst[0] = *(const bf16x8*)(cb + arowB + pcb); \
    dst[1] = *(const bf16x8*)(cb + arowB + 4096 + pcb); \
    dst[2] = *(const bf16x8*)(cb + arowB + 8192 + pcb); \
    dst[3] = *(const bf16x8*)(cb + arowB + 12288 + pcb); \
    dst[4] = *(const bf16x8*)(cb + browB + pcb); \
    dst[5] = *(const bf16x8*)(cb + browB + 4096 + pcb); }
  #define MFMA_KK4(f) { \
    __builtin_amdgcn_s_setprio(1); \
    acc[0][0] = __builtin_amdgcn_mfma_f32_32x32x16_bf16(f[0], f[4], acc[0][0], 0, 0, 0); \
    acc[0][1] = __builtin_amdgcn_mfma_f32_32x32x16_bf16(f[0], f[5], acc[0][1], 0, 0, 0); \
    acc[1][0] = __builtin_amdgcn_mfma_f32_32x32x16_bf16(f[1], f[4], acc[1][0], 0, 0, 0); \
    acc[1][1] = __builtin_amdgcn_mfma_f32_32x32x16_bf16(f[1], f[5], acc[1][1], 0, 0, 0); \
    acc[2][0] = __builtin_amdgcn_mfma_f32_32x32x16_bf16(f[2], f[4], acc[2][0], 0, 0, 0); \
    acc[2][1] = __builtin_amdgcn_mfma_f32_32x32x16_bf16(f[2], f[5], acc[2][1], 0, 0, 0); \
    acc[3][0] = __builtin_amdgcn_mfma_f32_32x32x16_bf16(f[3], f[4], acc[3][0], 0, 0, 0); \
    acc[3][1] = __builtin_amdgcn_mfma_f32_32x32x16_bf16(f[3], f[5], acc[3][1], 0, 0, 0); \
    __builtin_amdgcn_s_setprio(0); }

  for (int tt = 0; tt < nt; ++tt) {
    const long sk = (long)((tt + 1 < nt) ? (tt + 1) : (nt - 1)) * 64;
    bf16x8 f0[6], f1[6];
    READ_KK4(f0, 0);
    gload_lds16(pA[0] + sk, sb + dS[0]);
    gload_lds16(pA[1] + sk, sb + dS[1]);
    READ_KK4(f1, 1);
    gload_lds16(pA[2] + sk, sb + dS[2]);
    gload_lds16(pA[3] + sk, sb + dS[3]);
    MFMA_KK4(f0);
    gload_lds16(pB[0] + sk, sb + 32768 + dS[0]);
    gload_lds16(pB[1] + sk, sb + 32768 + dS[1]);
    MFMA_KK4(f1);
    READ_KK4(f0, 2);
    gload_lds16(pB[2] + sk, sb + 32768 + dS[2]);
    gload_lds16(pB[3] + sk, sb + 32768 + dS[3]);
    MFMA_KK4(f0);
    READ_KK4(f1, 3);
    MFMA_KK4(f1);
    asm volatile("s_waitcnt vmcnt(0)" ::: "memory");
    __builtin_amdgcn_s_barrier();
    __builtin_amdgcn_sched_barrier(0);
    char* tmp = cb; cb = sb; sb = tmp;
  }
  #undef READ_KK4
  #undef MFMA_KK4

  #pragma unroll
  for (int mf = 0; mf < 4; ++mf)
    #pragma unroll
    for (int nf = 0; nf < 2; ++nf)
      #pragma unroll
      for (int r = 0; r < 16; ++r) {
        long row = bm * 256 + wr * 128 + mf * 32 + (r & 3) + 8 * (r >> 2) + 4 * g2;
        long col = bn * 256 + wc * 64 + nf * 32 + l31;
        float v = acc[mf][nf][r];
        if constexpr (sizeof(OutT) == 2) C[row * N + col] = f2bf(v);
        else                             C[row * N + col] = v;
      }
}

// ---------------- stage 2: headwise LN + RoPE(GPT-J) + scale ----------------
__device__ __forceinline__ void ln_rope_head(const u16* __restrict__ src,
                                             const float* __restrict__ wgt,
                                             u16* __restrict__ dst,
                                             int lane, float sa, float ca, float scale) {
  u32 xr = *(const u32*)(src + 2 * lane);
  float x1 = bf2f((u16)(xr & 0xffffu)), x2 = bf2f((u16)(xr >> 16));
  float ssum = x1 + x2;
  #pragma unroll
  for (int off = 1; off < 64; off <<= 1) ssum += __shfl_xor(ssum, off);
  float mean = ssum * (1.0f / 128.0f);
  float e1 = x1 - mean, e2 = x2 - mean;
  float vv = e1 * e1 + e2 * e2;
  #pragma unroll
  for (int off = 1; off < 64; off <<= 1) vv += __shfl_xor(vv, off);
  float rstd = rsqrtf(vv * (1.0f / 128.0f) + LN_EPS);
  float y1 = e1 * rstd * wgt[2 * lane];
  float y2 = e2 * rstd * wgt[2 * lane + 1];
  float o1 = (y1 * ca - y2 * sa) * scale;
  float o2 = (y2 * ca + y1 * sa) * scale;
  *(u32*)(dst + 2 * lane) = (u32)f2bf(o1) | ((u32)f2bf(o2) << 16);
}

__global__ __launch_bounds__(512)
void ln_rope(const u16* __restrict__ qkv, const int* __restrict__ pos,
             const float* __restrict__ qw, const float* __restrict__ kw,
             u16* __restrict__ qo, u16* __restrict__ ko) {
  const int s = blockIdx.x, b = blockIdx.y;
  const int t = threadIdx.x, lane = t & 63, w = t >> 6; // 8 waves
  const long base = (long)(b * SEQ + s) * QKV_N;
  const int p = pos[b * SEQ + s];
  const float expo = (float)(2 * lane) * (1.0f / 128.0f);
  const float inv_freq = exp2f(-expo * 13.287712379549449f); // log2(10000)
  float sa, ca;
  sincosf((float)p * inv_freq, &sa, &ca);
  #pragma unroll
  for (int hh = 0; hh < 4; ++hh) {
    int h = w + hh * 8;
    ln_rope_head(qkv + base + h * HD, qw + h * HD,
                 qo + (((long)b * NH + h) * SEQ + s) * HD, lane, sa, ca,
                 ATT_SCALE * LOG2E);  // fold log2e: flash uses exp2
  }
  ln_rope_head(qkv + base + QSZ + w * HD, kw + w * HD,
               ko + (((long)b * NKV + w) * SEQ + s) * HD, lane, sa, ca, 1.0f);
}

// ---------------- stage 2b: V slice of qkv -> V^T [b][kvh][d][S] ------------
__global__ __launch_bounds__(256)
void v_transp(const u16* __restrict__ qkv, u16* __restrict__ vt) {
  __shared__ u16 tile[32][33];
  int s0 = blockIdx.x * 32, d0 = blockIdx.y * 32;
  int bk = blockIdx.z;                 // b*NKV + kvh
  int b = bk >> 3, kvh = bk & 7;
  int tx = threadIdx.x & 31, ty = threadIdx.x >> 5;
  const u16* src = qkv + ((long)(b * SEQ) + s0) * QKV_N + QSZ + KVSZ + kvh * HD + d0;
  #pragma unroll
  for (int j = 0; j < 32; j += 8)
    tile[ty + j][tx] = src[(long)(ty + j) * QKV_N + tx];
  __syncthreads();
  u16* dst = vt + (((long)bk) * HD + d0) * SEQ + s0;
  #pragma unroll
  for (int j = 0; j < 32; j += 8)
    dst[(long)(ty + j) * SEQ + tx] = tile[tx][ty + j];
}

// ---------------- stage 3: balanced causal GQA flash attention --------------
// 256 blocks (1/CU) x 512 thr; block (b,h,qp) processes q-tiles {7-qp, qp}:
// causal work = 36 KV-tiles/block, perfectly balanced.
__global__ __launch_bounds__(512, 2)
void flash_attn3(const u16* __restrict__ Qg, const u16* __restrict__ Kg,
                 const u16* __restrict__ Vtg, u16* __restrict__ Og) {
  const int lin = blockIdx.x;          // 256 blocks
  const int b = lin >> 7;
  const int rem = lin & 127;
  const int h = rem >> 2;
  const int qp = rem & 3;
  const int kvh = h >> 2;
  const int t = threadIdx.x, lane = t & 63, w = t >> 6;
  const int hh = lane >> 5, l31 = lane & 31;

  __shared__ u16 Klds[2][64 * 128];   // 2 x 16KB
  __shared__ u16 Vlds[2][128 * 64];   // 2 x 16KB

  const u16* Kbase = Kg + ((long)b * NKV + kvh) * (long)SEQ * HD;   // [kv][128]
  const u16* Vtbase = Vtg + ((long)b * NKV + kvh) * (long)HD * SEQ; // [d][2048]

  auto STAGE = [&](int buf, int kt) {
    const int kv0 = kt * 64;
    #pragma unroll
    for (int i = 0; i < 2; ++i) {   // K: 1024 chunks of 16B
      int c = t + i * 512;
      int kv = c >> 4, cc = c & 15;
      int cl = (cc & 8) | ((cc ^ kv) & 7);      // inverse swizzle on source
      gload_lds16(Kbase + (long)(kv0 + kv) * HD + cl * 8,
                  (char*)(&Klds[buf][0]) + (i * 512 + w * 64) * 16);
    }
    #pragma unroll
    for (int i = 0; i < 2; ++i) {   // V^T: 1024 chunks of 16B
      int c = t + i * 512;
      int d = c >> 3, cc = c & 7;
      int cl = cc ^ (d & 7);
      gload_lds16(Vtbase + (long)d * SEQ + kv0 + cl * 8,
                  (char*)(&Vlds[buf][0]) + (i * 512 + w * 64) * 16);
    }
  };

  for (int seg = 0; seg < 2; ++seg) {
    const int qt = seg ? qp : (7 - qp);   // heavy first
    const int wq0 = qt * 256 + w * 32;
    const int q = wq0 + l31;
    const u16* Qbase = Qg + (((long)b * NH + h) * SEQ + q) * HD + hh * 8;
    bf16x8 qf[8];
    #pragma unroll
    for (int ks = 0; ks < 8; ++ks) qf[ks] = *(const bf16x8*)(Qbase + ks * 16);

    f32x16 o[4];
    #pragma unroll
    for (int i = 0; i < 4; ++i)
      #pragma unroll
      for (int r = 0; r < 16; ++r) o[i][r] = 0.f;
    float m = -1e30f, l = 0.f;
    const int nt = qt * 4 + 4;

    __syncthreads();                 // seg1: all waves done reading seg0's LDS
    STAGE(0, 0);
    __syncthreads();
    int cur = 0;
    for (int kt = 0; kt < nt; ++kt) {
      const int kv0 = kt * 64;
      if (kt + 1 < nt) STAGE(cur ^ 1, kt + 1);
      if (kv0 <= wq0 + 31) {
        const char* Kb = (const char*)(&Klds[cur][0]);
        const char* Vb = (const char*)(&Vlds[cur][0]);
        f32x16 st[2];
        #pragma unroll
        for (int tt = 0; tt < 2; ++tt)
          #pragma unroll
          for (int r = 0; r < 16; ++r) st[tt][r] = 0.f;
        __builtin_amdgcn_s_setprio(1);
        #pragma unroll
        for (int tt = 0; tt < 2; ++tt) {
          if (kv0 + tt * 32 <= wq0 + 31) {
            #pragma unroll
            for (int ks = 0; ks < 8; ++ks) {
              int ch = ks * 2 + hh;
              int pc = (ch & 8) | ((ch ^ l31) & 7);   // swizzled read
              bf16x8 kf = *(const bf16x8*)(Kb + (tt * 32 + l31) * 256 + pc * 16);
              st[tt] = __builtin_amdgcn_mfma_f32_32x32x16_bf16(kf, qf[ks], st[tt], 0, 0, 0);
            }
          }
        }
        __builtin_amdgcn_s_setprio(0);
        if (kv0 + 63 > wq0) {
          #pragma unroll
          for (int tt = 0; tt < 2; ++tt)
            #pragma unroll
            for (int r = 0; r < 16; ++r) {
              int kva = kv0 + tt * 32 + (r & 3) + 8 * (r >> 2) + 4 * hh;
              if (kva > q) st[tt][r] = -1e30f;
            }
        }
        float p0 = -1e30f, p1 = -1e30f, p2 = -1e30f, p3 = -1e30f;
        #pragma unroll
        for (int tt = 0; tt < 2; ++tt)
          #pragma unroll
          for (int r = 0; r < 16; r += 4) {
            p0 = fmaxf(p0, st[tt][r]);
            p1 = fmaxf(p1, st[tt][r + 1]);
            p2 = fmaxf(p2, st[tt][r + 2]);
            p3 = fmaxf(p3, st[tt][r + 3]);
          }
        float mx = fmaxf(fmaxf(p0, p1), fmaxf(p2, p3));
        mx = fmaxf(mx, __shfl_xor(mx, 32));
        if (!__all(mx - m <= THRD)) {            // defer-max (T13)
          float mn = fmaxf(m, mx);
          float sc = exp2f(m - mn);
          m = mn;
          float scr[16];
          #pragma unroll
          for (int r = 0; r < 16; ++r)
            scr[r] = __shfl(sc, (r & 3) + 8 * (r >> 2) + 4 * hh);
          #pragma unroll
          for (int db = 0; db < 4; ++db)
            #pragma unroll
            for (int r = 0; r < 16; ++r) o[db][r] *= scr[r];
          l *= sc;
        }
        float s0 = 0.f, s1 = 0.f, s2 = 0.f, s3 = 0.f;
        #pragma unroll
        for (int tt = 0; tt < 2; ++tt)
          #pragma unroll
          for (int r = 0; r < 16; r += 4) {
            float e0 = exp2f(st[tt][r] - m);
            float e1 = exp2f(st[tt][r + 1] - m);
            float e2 = exp2f(st[tt][r + 2] - m);
            float e3 = exp2f(st[tt][r + 3] - m);
            st[tt][r] = e0; st[tt][r + 1] = e1; st[tt][r + 2] = e2; st[tt][r + 3] = e3;
            s0 += e0; s1 += e1; s2 += e2; s3 += e3;
          }
        float rs = (s0 + s1) + (s2 + s3);
        rs += __shfl_xor(rs, 32);
        l += rs;
        bf16x8 pa[4];
        #pragma unroll
        for (int k4 = 0; k4 < 4; ++k4) {
          int s8 = (k4 & 1) * 8, tt = k4 >> 1;
          u32 x0 = (u32)f2bf(st[tt][s8 + 0]) | ((u32)f2bf(st[tt][s8 + 1]) << 16);
          u32 x1 = (u32)f2bf(st[tt][s8 + 2]) | ((u32)f2bf(st[tt][s8 + 3]) << 16);
          u32 y0 = (u32)f2bf(st[tt][s8 + 4]) | ((u32)f2bf(st[tt][s8 + 5]) << 16);
          u32 y1 = (u32)f2bf(st[tt][s8 + 6]) | ((u32)f2bf(st[tt][s8 + 7]) << 16);
          u32 x0s = (u32)__shfl_xor((int)x0, 32), x1s = (u32)__shfl_xor((int)x1, 32);
          u32 y0s = (u32)__shfl_xor((int)y0, 32), y1s = (u32)__shfl_xor((int)y1, 32);
          union { u32 u[4]; bf16x8 v; } pk;
          pk.u[0] = hh ? y0s : x0;
          pk.u[1] = hh ? y1s : x1;
          pk.u[2] = hh ? y0 : x0s;
          pk.u[3] = hh ? y1 : x1s;
          pa[k4] = pk.v;
        }
        __builtin_amdgcn_s_setprio(1);
        #pragma unroll
        for (int k4 = 0; k4 < 4; ++k4)
          #pragma unroll
          for (int db = 0; db < 4; ++db) {
            int ch = k4 * 2 + hh;
            int pcc = ch ^ (l31 & 7);
            bf16x8 vf = *(const bf16x8*)(Vb + (db * 32 + l31) * 128 + pcc * 16);
            o[db] = __builtin_amdgcn_mfma_f32_32x32x16_bf16(pa[k4], vf, o[db], 0, 0, 0);
          }
        __builtin_amdgcn_s_setprio(0);
      }
      __syncthreads();
      cur ^= 1;
    }
    float linv = 1.0f / l;
    float li[16];
    #pragma unroll
    for (int r = 0; r < 16; ++r)
      li[r] = __shfl(linv, (r & 3) + 8 * (r >> 2) + 4 * hh);
    #pragma unroll
    for (int db = 0; db < 4; ++db)
      #pragma unroll
      for (int r = 0; r < 16; ++r) {
        int qr = wq0 + (r & 3) + 8 * (r >> 2) + 4 * hh;
        Og[((long)b * SEQ + qr) * QSZ + h * HD + db * 32 + l31] = f2bf(o[db][r] * li[r]);
      }
  }
}

// ---------------- launch -----------------------------------------------------
extern "C" void kernel_launch(void* const* d_in, const int* in_sizes, int n_in,
                              void* d_out, int out_size, void* d_ws, size_t ws_size,
                              hipStream_t stream) {
  const int*   positions = (const int*)d_in[0];
  const float* hidden    = (const float*)d_in[1];
  const float* Wqkv      = (const float*)d_in[2];
  const float* qnw       = (const float*)d_in[3];
  const float* knw       = (const float*)d_in[4];
  const float* Wo        = (const float*)d_in[5];
  float* out = (float*)d_out;
  char* ws = (char*)d_ws;
  const size_t MB = 1024 * 1024;
  u16* hbf   = (u16*)(ws + 0);        // 32MB: hidden bf16 (dead after gemm1)
  u16* WqkvT = (u16*)(ws + 32 * MB);  // 48MB: Wqkv^T bf16 (dead after gemm1)
  u16* qkvb  = (u16*)(ws + 80 * MB);  // 48MB: qkv bf16 (dead after ln_rope+v_transp)
  u16* q_arr = (u16*)(ws + 0);        // 32MB (aliases hbf)
  u16* k_arr = (u16*)(ws + 32 * MB);  //  8MB (aliases WqkvT[0:8M])
  u16* vt_arr= (u16*)(ws + 40 * MB);  //  8MB V^T [b][kvh][d][S]
  u16* WoT   = (u16*)(ws + 48 * MB);  // 32MB (aliases WqkvT[16M:48M])
  u16* Oarr  = (u16*)(ws + 80 * MB);  // 32MB (aliases qkvb[0:32M])

  const int GEMM9_LDS = 3 * 24576;    // 72 KB (QKV GEMM, 2 blocks/CU)
  const int GEMM4_LDS = 2 * 65536;    // 128 KB (out GEMM)
  (void)hipFuncSetAttribute((const void*)&gemm_bt9<u16>,
        hipFuncAttributeMaxDynamicSharedMemorySize, GEMM9_LDS);
  (void)hipFuncSetAttribute((const void*)&gemm_bt4<float>,
        hipFuncAttributeMaxDynamicSharedMemorySize, GEMM4_LDS);

  conv_f32_bf16<<<dim3(NTOK * HIDDEN / 8 / 256), 256, 0, stream>>>(hidden, hbf, NTOK * HIDDEN / 8);
  transp_f32_bf16<<<dim3(QKV_N / 32, HIDDEN / 32), 256, 0, stream>>>(Wqkv, WqkvT, HIDDEN, QKV_N);
  gemm_bt9<u16><<<dim3(QKV_N / 256, NTOK / 128), 512, GEMM9_LDS, stream>>>(hbf, WqkvT, qkvb, QKV_N, HIDDEN);
  ln_rope<<<dim3(SEQ, NB), 512, 0, stream>>>(qkvb, positions, qnw, knw, q_arr, k_arr);
  v_transp<<<dim3(SEQ / 32, HD / 32, NB * NKV), 256, 0, stream>>>(qkvb, vt_arr);
  transp_f32_bf16<<<dim3(HIDDEN / 32, QSZ / 32), 256, 0, stream>>>(Wo, WoT, QSZ, HIDDEN);
  flash_attn3<<<dim3(256), 512, 0, stream>>>(q_arr, k_arr, vt_arr, Oarr);
  gemm_bt4<float><<<dim3(HIDDEN / 256, NTOK / 256), 512, GEMM4_LDS, stream>>>(Oarr, WoT, out, HIDDEN, QSZ);
}

// Round 17
// 565.567 us; speedup vs baseline: 1.0583x; 1.0228x over previous
//
#include <hip/hip_runtime.h>
#include <hip/hip_bf16.h>
#include <cstdint>

typedef unsigned short u16;
typedef unsigned int u32;
typedef __attribute__((ext_vector_type(8))) short bf16x8;
typedef __attribute__((ext_vector_type(4))) float f32x4;
typedef __attribute__((ext_vector_type(16))) float f32x16;
typedef __attribute__((ext_vector_type(4))) unsigned int u32x4;

#define HIDDEN 4096
#define NH 32
#define NKV 8
#define HD 128
#define QSZ 4096
#define KVSZ 1024
#define QKV_N 6144
#define SEQ 2048
#define NB 2
#define NTOK (NB*SEQ)
#define ATT_SCALE 0.08838834764831845f
#define LOG2E 1.4426950408889634f
#define LN_EPS 1e-5f
#define THRD 12.0f   // defer-max threshold (log2 domain)

__device__ __forceinline__ u16 f2bf(float f) {
  union { float f; u32 u; } a; a.f = f;
  u32 r = a.u + 0x7fffu + ((a.u >> 16) & 1u);
  return (u16)(r >> 16);
}
__device__ __forceinline__ float bf2f(u16 h) {
  union { u32 u; float f; } a; a.u = ((u32)h) << 16;
  return a.f;
}

__device__ __forceinline__ void gload_lds16(const void* g, void* l) {
  __builtin_amdgcn_global_load_lds(
      (const __attribute__((address_space(1))) void*)g,
      (__attribute__((address_space(3))) void*)l,
      16, 0, 0);
}

// ---------------- stage 0a: f32 -> bf16 flat convert (8 elems/thread) -------
__global__ __launch_bounds__(256)
void conv_f32_bf16(const float* __restrict__ in, u16* __restrict__ out, int n8) {
  int i = blockIdx.x * 256 + threadIdx.x;
  if (i >= n8) return;
  const float4* p = (const float4*)in + (size_t)i * 2;
  float4 v0 = p[0], v1 = p[1];
  u32x4 o;
  o.x = (u32)f2bf(v0.x) | ((u32)f2bf(v0.y) << 16);
  o.y = (u32)f2bf(v0.z) | ((u32)f2bf(v0.w) << 16);
  o.z = (u32)f2bf(v1.x) | ((u32)f2bf(v1.y) << 16);
  o.w = (u32)f2bf(v1.z) | ((u32)f2bf(v1.w) << 16);
  ((u32x4*)out)[i] = o;
}

// ---------------- stage 0b: f32 [R][C] -> bf16 [C][R] transpose -------------
__global__ __launch_bounds__(256)
void transp_f32_bf16(const float* __restrict__ in, u16* __restrict__ out, int R, int C) {
  __shared__ float tile[32][33];
  int c0 = blockIdx.x << 5, r0 = blockIdx.y << 5;
  int tx = threadIdx.x & 31, ty = threadIdx.x >> 5; // 32 x 8
  #pragma unroll
  for (int j = 0; j < 32; j += 8)
    tile[ty + j][tx] = in[(long)(r0 + ty + j) * C + c0 + tx];
  __syncthreads();
  #pragma unroll
  for (int j = 0; j < 32; j += 8)
    out[(long)(c0 + ty + j) * R + r0 + tx] = f2bf(tile[tx][ty + j]);
}

// ---------------- GEMM A (r8-verified, best QKV): BM=128 BN=256 BK=64 -------
// 8 waves (2x4) of 64x64; mfma 32x32x16; 3-buffer LDS ring, counted vmcnt(6)
// once per K-tile (never drains), ONE barrier per K-tile. 8-chunk XOR swizzle
// p = c ^ (row&7) via pre-swizzled global source.
template<typename OutT>
__global__ __launch_bounds__(512, 2)
void gemm_bt6(const u16* __restrict__ A, const u16* __restrict__ Bt,
              OutT* __restrict__ C, int N, int K) {
  extern __shared__ char smem[];            // 3 * 49152 bytes
  const int t = threadIdx.x;
  const int lane = t & 63, w = t >> 6;
  const int wr = w >> 2, wc = w & 3;
  const int l31 = lane & 31, l7 = lane & 7, g2 = lane >> 5;
  const int bm = blockIdx.y, bn = blockIdx.x;

  const int ciA0 = t, ciA1 = t + 512;
  const u16* AgS0 = A + (long)(bm * 128 + (ciA0 >> 3)) * K + (((ciA0 & 7) ^ ((ciA0 >> 3) & 7)) << 3);
  const u16* AgS1 = A + (long)(bm * 128 + (ciA1 >> 3)) * K + (((ciA1 & 7) ^ ((ciA1 >> 3) & 7)) << 3);
  const u16* BgS0;
  const u16* BgS1;
  const u16* BgS2;
  const u16* BgS3;
  {
    int ci0 = t, ci1 = t + 512, ci2 = t + 1024, ci3 = t + 1536;
    BgS0 = Bt + (long)(bn * 256 + (ci0 >> 3)) * K + (((ci0 & 7) ^ ((ci0 >> 3) & 7)) << 3);
    BgS1 = Bt + (long)(bn * 256 + (ci1 >> 3)) * K + (((ci1 & 7) ^ ((ci1 >> 3) & 7)) << 3);
    BgS2 = Bt + (long)(bn * 256 + (ci2 >> 3)) * K + (((ci2 & 7) ^ ((ci2 >> 3) & 7)) << 3);
    BgS3 = Bt + (long)(bn * 256 + (ci3 >> 3)) * K + (((ci3 & 7) ^ ((ci3 >> 3) & 7)) << 3);
  }
  const int dA0 = (w * 64) * 16;
  const int dA1 = (512 + w * 64) * 16;
  const int dB0 = 16384 + (w * 64) * 16;
  const int dB1 = 16384 + (512 + w * 64) * 16;
  const int dB2 = 16384 + (1024 + w * 64) * 16;
  const int dB3 = 16384 + (1536 + w * 64) * 16;

  const int arow0 = (wr * 64 + l31) * 128;
  const int brow0 = 16384 + (wc * 64 + l31) * 128;

  f32x16 acc[2][2];
  #pragma unroll
  for (int i = 0; i < 2; ++i)
    #pragma unroll
    for (int j = 0; j < 2; ++j)
      #pragma unroll
      for (int r = 0; r < 16; ++r) acc[i][j][r] = 0.f;

  const int nt = K >> 6;
  char* cbase = smem;
  char* nbase = smem + 49152;
  char* sbase = smem + 98304;

  #define STAGE6(dst, koff) { \
    gload_lds16(AgS0 + (koff), dst + dA0);  gload_lds16(AgS1 + (koff), dst + dA1); \
    gload_lds16(BgS0 + (koff), dst + dB0);  gload_lds16(BgS1 + (koff), dst + dB1); \
    gload_lds16(BgS2 + (koff), dst + dB2);  gload_lds16(BgS3 + (koff), dst + dB3); }

  STAGE6(cbase, 0);
  STAGE6(nbase, 64);
  asm volatile("s_waitcnt vmcnt(6)" ::: "memory");
  __builtin_amdgcn_s_barrier();
  __builtin_amdgcn_sched_barrier(0);

  #define READ_KK6(dst, kkv) { \
    const int pcb = (((kkv) * 2 + g2) ^ l7) * 16; \
    dst[0] = *(const bf16x8*)(cbase + arow0 + pcb); \
    dst[1] = *(const bf16x8*)(cbase + arow0 + 32 * 128 + pcb); \
    dst[2] = *(const bf16x8*)(cbase + brow0 + pcb); \
    dst[3] = *(const bf16x8*)(cbase + brow0 + 32 * 128 + pcb); }
  #define MFMA_KK6(f) { \
    __builtin_amdgcn_s_setprio(1); \
    acc[0][0] = __builtin_amdgcn_mfma_f32_32x32x16_bf16(f[0], f[2], acc[0][0], 0, 0, 0); \
    acc[0][1] = __builtin_amdgcn_mfma_f32_32x32x16_bf16(f[0], f[3], acc[0][1], 0, 0, 0); \
    acc[1][0] = __builtin_amdgcn_mfma_f32_32x32x16_bf16(f[1], f[2], acc[1][0], 0, 0, 0); \
    acc[1][1] = __builtin_amdgcn_mfma_f32_32x32x16_bf16(f[1], f[3], acc[1][1], 0, 0, 0); \
    __builtin_amdgcn_s_setprio(0); }

  for (int tt = 0; tt < nt; ++tt) {
    const long sk = (long)((tt + 2 < nt) ? (tt + 2) : (nt - 1)) * 64;
    STAGE6(sbase, sk);
    bf16x8 fA[4], fB[4], fC[4], fD[4];
    READ_KK6(fA, 0);
    READ_KK6(fB, 1);
    MFMA_KK6(fA);
    READ_KK6(fC, 2);
    MFMA_KK6(fB);
    READ_KK6(fD, 3);
    MFMA_KK6(fC);
    MFMA_KK6(fD);
    asm volatile("s_waitcnt vmcnt(6)" ::: "memory");
    __builtin_amdgcn_s_barrier();
    __builtin_amdgcn_sched_barrier(0);
    char* tmp = cbase; cbase = nbase; nbase = sbase; sbase = tmp;
  }
  #undef READ_KK6
  #undef MFMA_KK6
  #undef STAGE6

  #pragma unroll
  for (int mf = 0; mf < 2; ++mf)
    #pragma unroll
    for (int nf = 0; nf < 2; ++nf)
      #pragma unroll
      for (int r = 0; r < 16; ++r) {
        long row = bm * 128 + wr * 64 + mf * 32 + (r & 3) + 8 * (r >> 2) + 4 * g2;
        long col = bn * 256 + wc * 64 + nf * 32 + l31;
        float v = acc[mf][nf][r];
        if constexpr (sizeof(OutT) == 2) C[row * N + col] = f2bf(v);
        else                             C[row * N + col] = v;
      }
}

// ---------------- GEMM B (r6-verified, best out-GEMM): BM=BN=256 BK=64 ------
// 8 waves (2M x 4N), wave-tile 128x64; 2-buffer LDS (128KB); stage loads
// interleaved mid-tile; one vmcnt(0)+barrier per K-tile. 8-chunk XOR swizzle.
template<typename OutT>
__global__ __launch_bounds__(512, 2)
void gemm_bt4(const u16* __restrict__ A, const u16* __restrict__ Bt,
              OutT* __restrict__ C, int N, int K) {
  extern __shared__ char smem[];            // 2 * 65536 bytes
  const int t = threadIdx.x;
  const int lane = t & 63, w = t >> 6;
  const int wr = w >> 2, wc = w & 3;
  const int l31 = lane & 31, g2 = lane >> 5;
  const int bm = blockIdx.y, bn = blockIdx.x;

  const u16* pA[4]; const u16* pB[4];
  int dS[4];
  #pragma unroll
  for (int i = 0; i < 4; ++i) {
    int ci = t + i * 512;
    int row = ci >> 3;
    int c = (ci & 7) ^ (row & 7);
    pA[i] = A  + (long)(bm * 256 + row) * K + (c << 3);
    pB[i] = Bt + (long)(bn * 256 + row) * K + (c << 3);
    dS[i] = (i * 512 + w * 64) * 16;
  }

  const int arowB = (wr * 128 + l31) * 128;
  const int browB = 32768 + (wc * 64 + l31) * 128;

  f32x16 acc[4][2];
  #pragma unroll
  for (int i = 0; i < 4; ++i)
    #pragma unroll
    for (int j = 0; j < 2; ++j)
      #pragma unroll
      for (int r = 0; r < 16; ++r) acc[i][j][r] = 0.f;

  const int nt = K >> 6;
  char* cb = smem;
  char* sb = smem + 65536;

  #pragma unroll
  for (int i = 0; i < 4; ++i) gload_lds16(pA[i], cb + dS[i]);
  #pragma unroll
  for (int i = 0; i < 4; ++i) gload_lds16(pB[i], cb + 32768 + dS[i]);
  asm volatile("s_waitcnt vmcnt(0)" ::: "memory");
  __builtin_amdgcn_s_barrier();
  __builtin_amdgcn_sched_barrier(0);

  #define READ_KK4(dst, kkv) { \
    const int pcb = ((((kkv) * 2 + g2)) ^ (l31 & 7)) << 4; \
    dst[0] = *(const bf16x8*)(cb + arowB + pcb); \
    dst[1] = *(const bf16x8*)(cb + arowB + 4096 + pcb); \
    dst[2] = *(const bf16x8*)(cb + arowB + 8192 + pcb); \
    dst[3] = *(const bf16x8*)(cb + arowB + 12288 + pcb); \
    dst[4] = *(const bf16x8*)(cb + browB + pcb); \
    dst[5] = *(const bf16x8*)(cb + browB + 4096 + pcb); }
  #define MFMA_KK4(f) { \
    __builtin_amdgcn_s_setprio(1); \
    acc[0][0] = __builtin_amdgcn_mfma_f32_32x32x16_bf16(f[0], f[4], acc[0][0], 0, 0, 0); \
    acc[0][1] = __builtin_amdgcn_mfma_f32_32x32x16_bf16(f[0], f[5], acc[0][1], 0, 0, 0); \
    acc[1][0] = __builtin_amdgcn_mfma_f32_32x32x16_bf16(f[1], f[4], acc[1][0], 0, 0, 0); \
    acc[1][1] = __builtin_amdgcn_mfma_f32_32x32x16_bf16(f[1], f[5], acc[1][1], 0, 0, 0); \
    acc[2][0] = __builtin_amdgcn_mfma_f32_32x32x16_bf16(f[2], f[4], acc[2][0], 0, 0, 0); \
    acc[2][1] = __builtin_amdgcn_mfma_f32_32x32x16_bf16(f[2], f[5], acc[2][1], 0, 0, 0); \
    acc[3][0] = __builtin_amdgcn_mfma_f32_32x32x16_bf16(f[3], f[4], acc[3][0], 0, 0, 0); \
    acc[3][1] = __builtin_amdgcn_mfma_f32_32x32x16_bf16(f[3], f[5], acc[3][1], 0, 0, 0); \
    __builtin_amdgcn_s_setprio(0); }

  for (int tt = 0; tt < nt; ++tt) {
    const long sk = (long)((tt + 1 < nt) ? (tt + 1) : (nt - 1)) * 64;
    bf16x8 f0[6], f1[6];
    READ_KK4(f0, 0);
    gload_lds16(pA[0] + sk, sb + dS[0]);
    gload_lds16(pA[1] + sk, sb + dS[1]);
    READ_KK4(f1, 1);
    gload_lds16(pA[2] + sk, sb + dS[2]);
    gload_lds16(pA[3] + sk, sb + dS[3]);
    MFMA_KK4(f0);
    gload_lds16(pB[0] + sk, sb + 32768 + dS[0]);
    gload_lds16(pB[1] + sk, sb + 32768 + dS[1]);
    MFMA_KK4(f1);
    READ_KK4(f0, 2);
    gload_lds16(pB[2] + sk, sb + 32768 + dS[2]);
    gload_lds16(pB[3] + sk, sb + 32768 + dS[3]);
    MFMA_KK4(f0);
    READ_KK4(f1, 3);
    MFMA_KK4(f1);
    asm volatile("s_waitcnt vmcnt(0)" ::: "memory");
    __builtin_amdgcn_s_barrier();
    __builtin_amdgcn_sched_barrier(0);
    char* tmp = cb; cb = sb; sb = tmp;
  }
  #undef READ_KK4
  #undef MFMA_KK4

  #pragma unroll
  for (int mf = 0; mf < 4; ++mf)
    #pragma unroll
    for (int nf = 0; nf < 2; ++nf)
      #pragma unroll
      for (int r = 0; r < 16; ++r) {
        long row = bm * 256 + wr * 128 + mf * 32 + (r & 3) + 8 * (r >> 2) + 4 * g2;
        long col = bn * 256 + wc * 64 + nf * 32 + l31;
        float v = acc[mf][nf][r];
        if constexpr (sizeof(OutT) == 2) C[row * N + col] = f2bf(v);
        else                             C[row * N + col] = v;
      }
}

// ---------------- stage 2: headwise LN + RoPE(GPT-J) + scale ----------------
__device__ __forceinline__ void ln_rope_head(const u16* __restrict__ src,
                                             const float* __restrict__ wgt,
                                             u16* __restrict__ dst,
                                             int lane, float sa, float ca, float scale) {
  u32 xr = *(const u32*)(src + 2 * lane);
  float x1 = bf2f((u16)(xr & 0xffffu)), x2 = bf2f((u16)(xr >> 16));
  float ssum = x1 + x2;
  #pragma unroll
  for (int off = 1; off < 64; off <<= 1) ssum += __shfl_xor(ssum, off);
  float mean = ssum * (1.0f / 128.0f);
  float e1 = x1 - mean, e2 = x2 - mean;
  float vv = e1 * e1 + e2 * e2;
  #pragma unroll
  for (int off = 1; off < 64; off <<= 1) vv += __shfl_xor(vv, off);
  float rstd = rsqrtf(vv * (1.0f / 128.0f) + LN_EPS);
  float y1 = e1 * rstd * wgt[2 * lane];
  float y2 = e2 * rstd * wgt[2 * lane + 1];
  float o1 = (y1 * ca - y2 * sa) * scale;
  float o2 = (y2 * ca + y1 * sa) * scale;
  *(u32*)(dst + 2 * lane) = (u32)f2bf(o1) | ((u32)f2bf(o2) << 16);
}

__global__ __launch_bounds__(512)
void ln_rope(const u16* __restrict__ qkv, const int* __restrict__ pos,
             const float* __restrict__ qw, const float* __restrict__ kw,
             u16* __restrict__ qo, u16* __restrict__ ko) {
  const int s = blockIdx.x, b = blockIdx.y;
  const int t = threadIdx.x, lane = t & 63, w = t >> 6; // 8 waves
  const long base = (long)(b * SEQ + s) * QKV_N;
  const int p = pos[b * SEQ + s];
  const float expo = (float)(2 * lane) * (1.0f / 128.0f);
  const float inv_freq = exp2f(-expo * 13.287712379549449f); // log2(10000)
  float sa, ca;
  sincosf((float)p * inv_freq, &sa, &ca);
  #pragma unroll
  for (int hh = 0; hh < 4; ++hh) {
    int h = w + hh * 8;
    ln_rope_head(qkv + base + h * HD, qw + h * HD,
                 qo + (((long)b * NH + h) * SEQ + s) * HD, lane, sa, ca,
                 ATT_SCALE * LOG2E);  // fold log2e: flash uses exp2
  }
  ln_rope_head(qkv + base + QSZ + w * HD, kw + w * HD,
               ko + (((long)b * NKV + w) * SEQ + s) * HD, lane, sa, ca, 1.0f);
}

// ---------------- stage 2b: V slice of qkv -> V^T [b][kvh][d][S] ------------
__global__ __launch_bounds__(256)
void v_transp(const u16* __restrict__ qkv, u16* __restrict__ vt) {
  __shared__ u16 tile[32][33];
  int s0 = blockIdx.x * 32, d0 = blockIdx.y * 32;
  int bk = blockIdx.z;                 // b*NKV + kvh
  int b = bk >> 3, kvh = bk & 7;
  int tx = threadIdx.x & 31, ty = threadIdx.x >> 5;
  const u16* src = qkv + ((long)(b * SEQ) + s0) * QKV_N + QSZ + KVSZ + kvh * HD + d0;
  #pragma unroll
  for (int j = 0; j < 32; j += 8)
    tile[ty + j][tx] = src[(long)(ty + j) * QKV_N + tx];
  __syncthreads();
  u16* dst = vt + (((long)bk) * HD + d0) * SEQ + s0;
  #pragma unroll
  for (int j = 0; j < 32; j += 8)
    dst[(long)(ty + j) * SEQ + tx] = tile[tx][ty + j];
}

// ---------------- stage 3: balanced causal GQA flash attention --------------
// 256 blocks (1/CU) x 512 thr; block (b,h,qp) processes q-tiles {7-qp, qp}:
// causal work = 36 KV-tiles/block, perfectly balanced.
__global__ __launch_bounds__(512, 2)
void flash_attn3(const u16* __restrict__ Qg, const u16* __restrict__ Kg,
                 const u16* __restrict__ Vtg, u16* __restrict__ Og) {
  const int lin = blockIdx.x;          // 256 blocks
  const int b = lin >> 7;
  const int rem = lin & 127;
  const int h = rem >> 2;
  const int qp = rem & 3;
  const int kvh = h >> 2;
  const int t = threadIdx.x, lane = t & 63, w = t >> 6;
  const int hh = lane >> 5, l31 = lane & 31;

  __shared__ u16 Klds[2][64 * 128];   // 2 x 16KB
  __shared__ u16 Vlds[2][128 * 64];   // 2 x 16KB

  const u16* Kbase = Kg + ((long)b * NKV + kvh) * (long)SEQ * HD;   // [kv][128]
  const u16* Vtbase = Vtg + ((long)b * NKV + kvh) * (long)HD * SEQ; // [d][2048]

  auto STAGE = [&](int buf, int kt) {
    const int kv0 = kt * 64;
    #pragma unroll
    for (int i = 0; i < 2; ++i) {   // K: 1024 chunks of 16B
      int c = t + i * 512;
      int kv = c >> 4, cc = c & 15;
      int cl = (cc & 8) | ((cc ^ kv) & 7);      // inverse swizzle on source
      gload_lds16(Kbase + (long)(kv0 + kv) * HD + cl * 8,
                  (char*)(&Klds[buf][0]) + (i * 512 + w * 64) * 16);
    }
    #pragma unroll
    for (int i = 0; i < 2; ++i) {   // V^T: 1024 chunks of 16B
      int c = t + i * 512;
      int d = c >> 3, cc = c & 7;
      int cl = cc ^ (d & 7);
      gload_lds16(Vtbase + (long)d * SEQ + kv0 + cl * 8,
                  (char*)(&Vlds[buf][0]) + (i * 512 + w * 64) * 16);
    }
  };

  for (int seg = 0; seg < 2; ++seg) {
    const int qt = seg ? qp : (7 - qp);   // heavy first
    const int wq0 = qt * 256 + w * 32;
    const int q = wq0 + l31;
    const u16* Qbase = Qg + (((long)b * NH + h) * SEQ + q) * HD + hh * 8;
    bf16x8 qf[8];
    #pragma unroll
    for (int ks = 0; ks < 8; ++ks) qf[ks] = *(const bf16x8*)(Qbase + ks * 16);

    f32x16 o[4];
    #pragma unroll
    for (int i = 0; i < 4; ++i)
      #pragma unroll
      for (int r = 0; r < 16; ++r) o[i][r] = 0.f;
    float m = -1e30f, l = 0.f;
    const int nt = qt * 4 + 4;

    __syncthreads();                 // seg1: all waves done reading seg0's LDS
    STAGE(0, 0);
    __syncthreads();
    int cur = 0;
    for (int kt = 0; kt < nt; ++kt) {
      const int kv0 = kt * 64;
      if (kt + 1 < nt) STAGE(cur ^ 1, kt + 1);
      if (kv0 <= wq0 + 31) {
        const char* Kb = (const char*)(&Klds[cur][0]);
        const char* Vb = (const char*)(&Vlds[cur][0]);
        f32x16 st[2];
        #pragma unroll
        for (int tt = 0; tt < 2; ++tt)
          #pragma unroll
          for (int r = 0; r < 16; ++r) st[tt][r] = 0.f;
        __builtin_amdgcn_s_setprio(1);
        #pragma unroll
        for (int tt = 0; tt < 2; ++tt) {
          if (kv0 + tt * 32 <= wq0 + 31) {
            #pragma unroll
            for (int ks = 0; ks < 8; ++ks) {
              int ch = ks * 2 + hh;
              int pc = (ch & 8) | ((ch ^ l31) & 7);   // swizzled read
              bf16x8 kf = *(const bf16x8*)(Kb + (tt * 32 + l31) * 256 + pc * 16);
              st[tt] = __builtin_amdgcn_mfma_f32_32x32x16_bf16(kf, qf[ks], st[tt], 0, 0, 0);
            }
          }
        }
        __builtin_amdgcn_s_setprio(0);
        if (kv0 + 63 > wq0) {
          #pragma unroll
          for (int tt = 0; tt < 2; ++tt)
            #pragma unroll
            for (int r = 0; r < 16; ++r) {
              int kva = kv0 + tt * 32 + (r & 3) + 8 * (r >> 2) + 4 * hh;
              if (kva > q) st[tt][r] = -1e30f;
            }
        }
        float p0 = -1e30f, p1 = -1e30f, p2 = -1e30f, p3 = -1e30f;
        #pragma unroll
        for (int tt = 0; tt < 2; ++tt)
          #pragma unroll
          for (int r = 0; r < 16; r += 4) {
            p0 = fmaxf(p0, st[tt][r]);
            p1 = fmaxf(p1, st[tt][r + 1]);
            p2 = fmaxf(p2, st[tt][r + 2]);
            p3 = fmaxf(p3, st[tt][r + 3]);
          }
        float mx = fmaxf(fmaxf(p0, p1), fmaxf(p2, p3));
        mx = fmaxf(mx, __shfl_xor(mx, 32));
        if (!__all(mx - m <= THRD)) {            // defer-max (T13)
          float mn = fmaxf(m, mx);
          float sc = exp2f(m - mn);
          m = mn;
          float scr[16];
          #pragma unroll
          for (int r = 0; r < 16; ++r)
            scr[r] = __shfl(sc, (r & 3) + 8 * (r >> 2) + 4 * hh);
          #pragma unroll
          for (int db = 0; db < 4; ++db)
            #pragma unroll
            for (int r = 0; r < 16; ++r) o[db][r] *= scr[r];
          l *= sc;
        }
        float s0 = 0.f, s1 = 0.f, s2 = 0.f, s3 = 0.f;
        #pragma unroll
        for (int tt = 0; tt < 2; ++tt)
          #pragma unroll
          for (int r = 0; r < 16; r += 4) {
            float e0 = exp2f(st[tt][r] - m);
            float e1 = exp2f(st[tt][r + 1] - m);
            float e2 = exp2f(st[tt][r + 2] - m);
            float e3 = exp2f(st[tt][r + 3] - m);
            st[tt][r] = e0; st[tt][r + 1] = e1; st[tt][r + 2] = e2; st[tt][r + 3] = e3;
            s0 += e0; s1 += e1; s2 += e2; s3 += e3;
          }
        float rs = (s0 + s1) + (s2 + s3);
        rs += __shfl_xor(rs, 32);
        l += rs;
        bf16x8 pa[4];
        #pragma unroll
        for (int k4 = 0; k4 < 4; ++k4) {
          int s8 = (k4 & 1) * 8, tt = k4 >> 1;
          u32 x0 = (u32)f2bf(st[tt][s8 + 0]) | ((u32)f2bf(st[tt][s8 + 1]) << 16);
          u32 x1 = (u32)f2bf(st[tt][s8 + 2]) | ((u32)f2bf(st[tt][s8 + 3]) << 16);
          u32 y0 = (u32)f2bf(st[tt][s8 + 4]) | ((u32)f2bf(st[tt][s8 + 5]) << 16);
          u32 y1 = (u32)f2bf(st[tt][s8 + 6]) | ((u32)f2bf(st[tt][s8 + 7]) << 16);
          u32 x0s = (u32)__shfl_xor((int)x0, 32), x1s = (u32)__shfl_xor((int)x1, 32);
          u32 y0s = (u32)__shfl_xor((int)y0, 32), y1s = (u32)__shfl_xor((int)y1, 32);
          union { u32 u[4]; bf16x8 v; } pk;
          pk.u[0] = hh ? y0s : x0;
          pk.u[1] = hh ? y1s : x1;
          pk.u[2] = hh ? y0 : x0s;
          pk.u[3] = hh ? y1 : x1s;
          pa[k4] = pk.v;
        }
        __builtin_amdgcn_s_setprio(1);
        #pragma unroll
        for (int k4 = 0; k4 < 4; ++k4)
          #pragma unroll
          for (int db = 0; db < 4; ++db) {
            int ch = k4 * 2 + hh;
            int pcc = ch ^ (l31 & 7);
            bf16x8 vf = *(const bf16x8*)(Vb + (db * 32 + l31) * 128 + pcc * 16);
            o[db] = __builtin_amdgcn_mfma_f32_32x32x16_bf16(pa[k4], vf, o[db], 0, 0, 0);
          }
        __builtin_amdgcn_s_setprio(0);
      }
      __syncthreads();
      cur ^= 1;
    }
    float linv = 1.0f / l;
    float li[16];
    #pragma unroll
    for (int r = 0; r < 16; ++r)
      li[r] = __shfl(linv, (r & 3) + 8 * (r >> 2) + 4 * hh);
    #pragma unroll
    for (int db = 0; db < 4; ++db)
      #pragma unroll
      for (int r = 0; r < 16; ++r) {
        int qr = wq0 + (r & 3) + 8 * (r >> 2) + 4 * hh;
        Og[((long)b * SEQ + qr) * QSZ + h * HD + db * 32 + l31] = f2bf(o[db][r] * li[r]);
      }
  }
}

// ---------------- launch -----------------------------------------------------
extern "C" void kernel_launch(void* const* d_in, const int* in_sizes, int n_in,
                              void* d_out, int out_size, void* d_ws, size_t ws_size,
                              hipStream_t stream) {
  const int*   positions = (const int*)d_in[0];
  const float* hidden    = (const float*)d_in[1];
  const float* Wqkv      = (const float*)d_in[2];
  const float* qnw       = (const float*)d_in[3];
  const float* knw       = (const float*)d_in[4];
  const float* Wo        = (const float*)d_in[5];
  float* out = (float*)d_out;
  char* ws = (char*)d_ws;
  const size_t MB = 1024 * 1024;
  u16* hbf   = (u16*)(ws + 0);        // 32MB: hidden bf16 (dead after gemm1)
  u16* WqkvT = (u16*)(ws + 32 * MB);  // 48MB: Wqkv^T bf16 (dead after gemm1)
  u16* qkvb  = (u16*)(ws + 80 * MB);  // 48MB: qkv bf16 (dead after ln_rope+v_transp)
  u16* q_arr = (u16*)(ws + 0);        // 32MB (aliases hbf)
  u16* k_arr = (u16*)(ws + 32 * MB);  //  8MB (aliases WqkvT[0:8M])
  u16* vt_arr= (u16*)(ws + 40 * MB);  //  8MB V^T [b][kvh][d][S]
  u16* WoT   = (u16*)(ws + 48 * MB);  // 32MB (aliases WqkvT[16M:48M])
  u16* Oarr  = (u16*)(ws + 80 * MB);  // 32MB (aliases qkvb[0:32M])

  const int GEMM6_LDS = 3 * 49152;    // 144 KB (QKV GEMM)
  const int GEMM4_LDS = 2 * 65536;    // 128 KB (out GEMM)
  (void)hipFuncSetAttribute((const void*)&gemm_bt6<u16>,
        hipFuncAttributeMaxDynamicSharedMemorySize, GEMM6_LDS);
  (void)hipFuncSetAttribute((const void*)&gemm_bt4<float>,
        hipFuncAttributeMaxDynamicSharedMemorySize, GEMM4_LDS);

  conv_f32_bf16<<<dim3(NTOK * HIDDEN / 8 / 256), 256, 0, stream>>>(hidden, hbf, NTOK * HIDDEN / 8);
  transp_f32_bf16<<<dim3(QKV_N / 32, HIDDEN / 32), 256, 0, stream>>>(Wqkv, WqkvT, HIDDEN, QKV_N);
  gemm_bt6<u16><<<dim3(QKV_N / 256, NTOK / 128), 512, GEMM6_LDS, stream>>>(hbf, WqkvT, qkvb, QKV_N, HIDDEN);
  ln_rope<<<dim3(SEQ, NB), 512, 0, stream>>>(qkvb, positions, qnw, knw, q_arr, k_arr);
  v_transp<<<dim3(SEQ / 32, HD / 32, NB * NKV), 256, 0, stream>>>(qkvb, vt_arr);
  transp_f32_bf16<<<dim3(HIDDEN / 32, QSZ / 32), 256, 0, stream>>>(Wo, WoT, QSZ, HIDDEN);
  flash_attn3<<<dim3(256), 512, 0, stream>>>(q_arr, k_arr, vt_arr, Oarr);
  gemm_bt4<float><<<dim3(HIDDEN / 256, NTOK / 256), 512, GEMM4_LDS, stream>>>(Oarr, WoT, out, HIDDEN, QSZ);
}

// Round 19
// 561.401 us; speedup vs baseline: 1.0662x; 1.0074x over previous
//
#include <hip/hip_runtime.h>
#include <hip/hip_bf16.h>
#include <cstdint>

typedef unsigned short u16;
typedef unsigned int u32;
typedef __attribute__((ext_vector_type(8))) short bf16x8;
typedef __attribute__((ext_vector_type(4))) float f32x4;
typedef __attribute__((ext_vector_type(16))) float f32x16;
typedef __attribute__((ext_vector_type(4))) unsigned int u32x4;

#define HIDDEN 4096
#define NH 32
#define NKV 8
#define HD 128
#define QSZ 4096
#define KVSZ 1024
#define QKV_N 6144
#define SEQ 2048
#define NB 2
#define NTOK (NB*SEQ)
#define ATT_SCALE 0.08838834764831845f
#define LOG2E 1.4426950408889634f
#define LN_EPS 1e-5f
#define THRD 12.0f   // defer-max threshold (log2 domain)

__device__ __forceinline__ u16 f2bf(float f) {
  union { float f; u32 u; } a; a.f = f;
  u32 r = a.u + 0x7fffu + ((a.u >> 16) & 1u);
  return (u16)(r >> 16);
}
__device__ __forceinline__ float bf2f(u16 h) {
  union { u32 u; float f; } a; a.u = ((u32)h) << 16;
  return a.f;
}

__device__ __forceinline__ void gload_lds16(const void* g, void* l) {
  __builtin_amdgcn_global_load_lds(
      (const __attribute__((address_space(1))) void*)g,
      (__attribute__((address_space(3))) void*)l,
      16, 0, 0);
}

// ---------------- fused prep: conv(hidden) + transp(Wqkv) ONLY --------------
// (Wo transpose moved to ln_rope_v: WoT region aliases WqkvT, which is only
//  dead after the QKV GEMM — r18's concurrent write corrupted the weights.)
#define CONV_NBLK   (NTOK * HIDDEN / 8 / 256)          // 8192
#define TQKV_NBLK   ((QKV_N / 32) * (HIDDEN / 32))     // 24576

__global__ __launch_bounds__(256)
void prep_fused(const float* __restrict__ hidden, u16* __restrict__ hbf,
                const float* __restrict__ Wqkv, u16* __restrict__ WqkvT) {
  __shared__ float tile[32][33];
  const int bid = blockIdx.x;
  const int t = threadIdx.x;
  if (bid < CONV_NBLK) {
    int i = bid * 256 + t;
    const float4* p = (const float4*)hidden + (size_t)i * 2;
    float4 v0 = p[0], v1 = p[1];
    u32x4 o;
    o.x = (u32)f2bf(v0.x) | ((u32)f2bf(v0.y) << 16);
    o.y = (u32)f2bf(v0.z) | ((u32)f2bf(v0.w) << 16);
    o.z = (u32)f2bf(v1.x) | ((u32)f2bf(v1.y) << 16);
    o.w = (u32)f2bf(v1.z) | ((u32)f2bf(v1.w) << 16);
    ((u32x4*)hbf)[i] = o;
  } else {
    int T = bid - CONV_NBLK;
    int bx = T % (QKV_N / 32), by = T / (QKV_N / 32);   // 192 x 128
    int c0 = bx << 5, r0 = by << 5;
    int tx = t & 31, ty = t >> 5; // 32 x 8
    #pragma unroll
    for (int j = 0; j < 32; j += 8)
      tile[ty + j][tx] = Wqkv[(long)(r0 + ty + j) * QKV_N + c0 + tx];
    __syncthreads();
    #pragma unroll
    for (int j = 0; j < 32; j += 8)
      WqkvT[(long)(c0 + ty + j) * HIDDEN + r0 + tx] = f2bf(tile[tx][ty + j]);
  }
}

// ---------------- GEMM A (r8-verified, best QKV): BM=128 BN=256 BK=64 -------
// 8 waves (2x4) of 64x64; mfma 32x32x16; 3-buffer LDS ring, counted vmcnt(6)
// once per K-tile (never drains), ONE barrier per K-tile. 8-chunk XOR swizzle
// p = c ^ (row&7) via pre-swizzled global source.
template<typename OutT>
__global__ __launch_bounds__(512, 2)
void gemm_bt6(const u16* __restrict__ A, const u16* __restrict__ Bt,
              OutT* __restrict__ C, int N, int K) {
  extern __shared__ char smem[];            // 3 * 49152 bytes
  const int t = threadIdx.x;
  const int lane = t & 63, w = t >> 6;
  const int wr = w >> 2, wc = w & 3;
  const int l31 = lane & 31, l7 = lane & 7, g2 = lane >> 5;
  const int bm = blockIdx.y, bn = blockIdx.x;

  const int ciA0 = t, ciA1 = t + 512;
  const u16* AgS0 = A + (long)(bm * 128 + (ciA0 >> 3)) * K + (((ciA0 & 7) ^ ((ciA0 >> 3) & 7)) << 3);
  const u16* AgS1 = A + (long)(bm * 128 + (ciA1 >> 3)) * K + (((ciA1 & 7) ^ ((ciA1 >> 3) & 7)) << 3);
  const u16* BgS0;
  const u16* BgS1;
  const u16* BgS2;
  const u16* BgS3;
  {
    int ci0 = t, ci1 = t + 512, ci2 = t + 1024, ci3 = t + 1536;
    BgS0 = Bt + (long)(bn * 256 + (ci0 >> 3)) * K + (((ci0 & 7) ^ ((ci0 >> 3) & 7)) << 3);
    BgS1 = Bt + (long)(bn * 256 + (ci1 >> 3)) * K + (((ci1 & 7) ^ ((ci1 >> 3) & 7)) << 3);
    BgS2 = Bt + (long)(bn * 256 + (ci2 >> 3)) * K + (((ci2 & 7) ^ ((ci2 >> 3) & 7)) << 3);
    BgS3 = Bt + (long)(bn * 256 + (ci3 >> 3)) * K + (((ci3 & 7) ^ ((ci3 >> 3) & 7)) << 3);
  }
  const int dA0 = (w * 64) * 16;
  const int dA1 = (512 + w * 64) * 16;
  const int dB0 = 16384 + (w * 64) * 16;
  const int dB1 = 16384 + (512 + w * 64) * 16;
  const int dB2 = 16384 + (1024 + w * 64) * 16;
  const int dB3 = 16384 + (1536 + w * 64) * 16;

  const int arow0 = (wr * 64 + l31) * 128;
  const int brow0 = 16384 + (wc * 64 + l31) * 128;

  f32x16 acc[2][2];
  #pragma unroll
  for (int i = 0; i < 2; ++i)
    #pragma unroll
    for (int j = 0; j < 2; ++j)
      #pragma unroll
      for (int r = 0; r < 16; ++r) acc[i][j][r] = 0.f;

  const int nt = K >> 6;
  char* cbase = smem;
  char* nbase = smem + 49152;
  char* sbase = smem + 98304;

  #define STAGE6(dst, koff) { \
    gload_lds16(AgS0 + (koff), dst + dA0);  gload_lds16(AgS1 + (koff), dst + dA1); \
    gload_lds16(BgS0 + (koff), dst + dB0);  gload_lds16(BgS1 + (koff), dst + dB1); \
    gload_lds16(BgS2 + (koff), dst + dB2);  gload_lds16(BgS3 + (koff), dst + dB3); }

  STAGE6(cbase, 0);
  STAGE6(nbase, 64);
  asm volatile("s_waitcnt vmcnt(6)" ::: "memory");
  __builtin_amdgcn_s_barrier();
  __builtin_amdgcn_sched_barrier(0);

  #define READ_KK6(dst, kkv) { \
    const int pcb = (((kkv) * 2 + g2) ^ l7) * 16; \
    dst[0] = *(const bf16x8*)(cbase + arow0 + pcb); \
    dst[1] = *(const bf16x8*)(cbase + arow0 + 32 * 128 + pcb); \
    dst[2] = *(const bf16x8*)(cbase + brow0 + pcb); \
    dst[3] = *(const bf16x8*)(cbase + brow0 + 32 * 128 + pcb); }
  #define MFMA_KK6(f) { \
    __builtin_amdgcn_s_setprio(1); \
    acc[0][0] = __builtin_amdgcn_mfma_f32_32x32x16_bf16(f[0], f[2], acc[0][0], 0, 0, 0); \
    acc[0][1] = __builtin_amdgcn_mfma_f32_32x32x16_bf16(f[0], f[3], acc[0][1], 0, 0, 0); \
    acc[1][0] = __builtin_amdgcn_mfma_f32_32x32x16_bf16(f[1], f[2], acc[1][0], 0, 0, 0); \
    acc[1][1] = __builtin_amdgcn_mfma_f32_32x32x16_bf16(f[1], f[3], acc[1][1], 0, 0, 0); \
    __builtin_amdgcn_s_setprio(0); }

  for (int tt = 0; tt < nt; ++tt) {
    const long sk = (long)((tt + 2 < nt) ? (tt + 2) : (nt - 1)) * 64;
    STAGE6(sbase, sk);
    bf16x8 fA[4], fB[4], fC[4], fD[4];
    READ_KK6(fA, 0);
    READ_KK6(fB, 1);
    MFMA_KK6(fA);
    READ_KK6(fC, 2);
    MFMA_KK6(fB);
    READ_KK6(fD, 3);
    MFMA_KK6(fC);
    MFMA_KK6(fD);
    asm volatile("s_waitcnt vmcnt(6)" ::: "memory");
    __builtin_amdgcn_s_barrier();
    __builtin_amdgcn_sched_barrier(0);
    char* tmp = cbase; cbase = nbase; nbase = sbase; sbase = tmp;
  }
  #undef READ_KK6
  #undef MFMA_KK6
  #undef STAGE6

  #pragma unroll
  for (int mf = 0; mf < 2; ++mf)
    #pragma unroll
    for (int nf = 0; nf < 2; ++nf)
      #pragma unroll
      for (int r = 0; r < 16; ++r) {
        long row = bm * 128 + wr * 64 + mf * 32 + (r & 3) + 8 * (r >> 2) + 4 * g2;
        long col = bn * 256 + wc * 64 + nf * 32 + l31;
        float v = acc[mf][nf][r];
        if constexpr (sizeof(OutT) == 2) C[row * N + col] = f2bf(v);
        else                             C[row * N + col] = v;
      }
}

// ---------------- GEMM B (r6-verified, best out-GEMM): BM=BN=256 BK=64 ------
// 8 waves (2M x 4N), wave-tile 128x64; 2-buffer LDS (128KB); stage loads
// interleaved mid-tile; one vmcnt(0)+barrier per K-tile. 8-chunk XOR swizzle.
template<typename OutT>
__global__ __launch_bounds__(512, 2)
void gemm_bt4(const u16* __restrict__ A, const u16* __restrict__ Bt,
              OutT* __restrict__ C, int N, int K) {
  extern __shared__ char smem[];            // 2 * 65536 bytes
  const int t = threadIdx.x;
  const int lane = t & 63, w = t >> 6;
  const int wr = w >> 2, wc = w & 3;
  const int l31 = lane & 31, g2 = lane >> 5;
  const int bm = blockIdx.y, bn = blockIdx.x;

  const u16* pA[4]; const u16* pB[4];
  int dS[4];
  #pragma unroll
  for (int i = 0; i < 4; ++i) {
    int ci = t + i * 512;
    int row = ci >> 3;
    int c = (ci & 7) ^ (row & 7);
    pA[i] = A  + (long)(bm * 256 + row) * K + (c << 3);
    pB[i] = Bt + (long)(bn * 256 + row) * K + (c << 3);
    dS[i] = (i * 512 + w * 64) * 16;
  }

  const int arowB = (wr * 128 + l31) * 128;
  const int browB = 32768 + (wc * 64 + l31) * 128;

  f32x16 acc[4][2];
  #pragma unroll
  for (int i = 0; i < 4; ++i)
    #pragma unroll
    for (int j = 0; j < 2; ++j)
      #pragma unroll
      for (int r = 0; r < 16; ++r) acc[i][j][r] = 0.f;

  const int nt = K >> 6;
  char* cb = smem;
  char* sb = smem + 65536;

  #pragma unroll
  for (int i = 0; i < 4; ++i) gload_lds16(pA[i], cb + dS[i]);
  #pragma unroll
  for (int i = 0; i < 4; ++i) gload_lds16(pB[i], cb + 32768 + dS[i]);
  asm volatile("s_waitcnt vmcnt(0)" ::: "memory");
  __builtin_amdgcn_s_barrier();
  __builtin_amdgcn_sched_barrier(0);

  #define READ_KK4(dst, kkv) { \
    const int pcb = ((((kkv) * 2 + g2)) ^ (l31 & 7)) << 4; \
    dst[0] = *(const bf16x8*)(cb + arowB + pcb); \
    dst[1] = *(const bf16x8*)(cb + arowB + 4096 + pcb); \
    dst[2] = *(const bf16x8*)(cb + arowB + 8192 + pcb); \
    dst[3] = *(const bf16x8*)(cb + arowB + 12288 + pcb); \
    dst[4] = *(const bf16x8*)(cb + browB + pcb); \
    dst[5] = *(const bf16x8*)(cb + browB + 4096 + pcb); }
  #define MFMA_KK4(f) { \
    __builtin_amdgcn_s_setprio(1); \
    acc[0][0] = __builtin_amdgcn_mfma_f32_32x32x16_bf16(f[0], f[4], acc[0][0], 0, 0, 0); \
    acc[0][1] = __builtin_amdgcn_mfma_f32_32x32x16_bf16(f[0], f[5], acc[0][1], 0, 0, 0); \
    acc[1][0] = __builtin_amdgcn_mfma_f32_32x32x16_bf16(f[1], f[4], acc[1][0], 0, 0, 0); \
    acc[1][1] = __builtin_amdgcn_mfma_f32_32x32x16_bf16(f[1], f[5], acc[1][1], 0, 0, 0); \
    acc[2][0] = __builtin_amdgcn_mfma_f32_32x32x16_bf16(f[2], f[4], acc[2][0], 0, 0, 0); \
    acc[2][1] = __builtin_amdgcn_mfma_f32_32x32x16_bf16(f[2], f[5], acc[2][1], 0, 0, 0); \
    acc[3][0] = __builtin_amdgcn_mfma_f32_32x32x16_bf16(f[3], f[4], acc[3][0], 0, 0, 0); \
    acc[3][1] = __builtin_amdgcn_mfma_f32_32x32x16_bf16(f[3], f[5], acc[3][1], 0, 0, 0); \
    __builtin_amdgcn_s_setprio(0); }

  for (int tt = 0; tt < nt; ++tt) {
    const long sk = (long)((tt + 1 < nt) ? (tt + 1) : (nt - 1)) * 64;
    bf16x8 f0[6], f1[6];
    READ_KK4(f0, 0);
    gload_lds16(pA[0] + sk, sb + dS[0]);
    gload_lds16(pA[1] + sk, sb + dS[1]);
    READ_KK4(f1, 1);
    gload_lds16(pA[2] + sk, sb + dS[2]);
    gload_lds16(pA[3] + sk, sb + dS[3]);
    MFMA_KK4(f0);
    gload_lds16(pB[0] + sk, sb + 32768 + dS[0]);
    gload_lds16(pB[1] + sk, sb + 32768 + dS[1]);
    MFMA_KK4(f1);
    READ_KK4(f0, 2);
    gload_lds16(pB[2] + sk, sb + 32768 + dS[2]);
    gload_lds16(pB[3] + sk, sb + 32768 + dS[3]);
    MFMA_KK4(f0);
    READ_KK4(f1, 3);
    MFMA_KK4(f1);
    asm volatile("s_waitcnt vmcnt(0)" ::: "memory");
    __builtin_amdgcn_s_barrier();
    __builtin_amdgcn_sched_barrier(0);
    char* tmp = cb; cb = sb; sb = tmp;
  }
  #undef READ_KK4
  #undef MFMA_KK4

  #pragma unroll
  for (int mf = 0; mf < 4; ++mf)
    #pragma unroll
    for (int nf = 0; nf < 2; ++nf)
      #pragma unroll
      for (int r = 0; r < 16; ++r) {
        long row = bm * 256 + wr * 128 + mf * 32 + (r & 3) + 8 * (r >> 2) + 4 * g2;
        long col = bn * 256 + wc * 64 + nf * 32 + l31;
        float v = acc[mf][nf][r];
        if constexpr (sizeof(OutT) == 2) C[row * N + col] = f2bf(v);
        else                             C[row * N + col] = v;
      }
}

// ---------------- fused LN+RoPE + V-transpose + Wo-transpose ----------------
__device__ __forceinline__ void ln_rope_head(const u16* __restrict__ src,
                                             const float* __restrict__ wgt,
                                             u16* __restrict__ dst,
                                             int lane, float sa, float ca, float scale) {
  u32 xr = *(const u32*)(src + 2 * lane);
  float x1 = bf2f((u16)(xr & 0xffffu)), x2 = bf2f((u16)(xr >> 16));
  float ssum = x1 + x2;
  #pragma unroll
  for (int off = 1; off < 64; off <<= 1) ssum += __shfl_xor(ssum, off);
  float mean = ssum * (1.0f / 128.0f);
  float e1 = x1 - mean, e2 = x2 - mean;
  float vv = e1 * e1 + e2 * e2;
  #pragma unroll
  for (int off = 1; off < 64; off <<= 1) vv += __shfl_xor(vv, off);
  float rstd = rsqrtf(vv * (1.0f / 128.0f) + LN_EPS);
  float y1 = e1 * rstd * wgt[2 * lane];
  float y2 = e2 * rstd * wgt[2 * lane + 1];
  float o1 = (y1 * ca - y2 * sa) * scale;
  float o2 = (y2 * ca + y1 * sa) * scale;
  *(u32*)(dst + 2 * lane) = (u32)f2bf(o1) | ((u32)f2bf(o2) << 16);
}

// grid (SEQ + SEQ + 8192, NB), 512 thr.
//  x < SEQ:          ln_rope(s=x, b=y)
//  SEQ <= x < 2*SEQ: one 32x32 V-transpose tile, id2 = y*SEQ + (x-SEQ)
//  x >= 2*SEQ:       one 32x32 Wo-transpose tile, id3 = y*8192 + (x-2*SEQ)
//                    (WoT region aliases dead WqkvT -- safe after gemm_bt6)
__global__ __launch_bounds__(512)
void ln_rope_v(const u16* __restrict__ qkv, const int* __restrict__ pos,
               const float* __restrict__ qw, const float* __restrict__ kw,
               u16* __restrict__ qo, u16* __restrict__ ko,
               u16* __restrict__ vt,
               const float* __restrict__ Wo, u16* __restrict__ WoT) {
  __shared__ u16 tile[32][33];
  __shared__ float ftile[32][33];
  const int x = blockIdx.x, yb = blockIdx.y;
  const int t = threadIdx.x;
  if (x < SEQ) {
    const int s = x, b = yb;
    const int lane = t & 63, w = t >> 6; // 8 waves
    const long base = (long)(b * SEQ + s) * QKV_N;
    const int p = pos[b * SEQ + s];
    const float expo = (float)(2 * lane) * (1.0f / 128.0f);
    const float inv_freq = exp2f(-expo * 13.287712379549449f); // log2(10000)
    float sa, ca;
    sincosf((float)p * inv_freq, &sa, &ca);
    #pragma unroll
    for (int hh = 0; hh < 4; ++hh) {
      int h = w + hh * 8;
      ln_rope_head(qkv + base + h * HD, qw + h * HD,
                   qo + (((long)b * NH + h) * SEQ + s) * HD, lane, sa, ca,
                   ATT_SCALE * LOG2E);  // fold log2e: flash uses exp2
    }
    ln_rope_head(qkv + base + QSZ + w * HD, kw + w * HD,
                 ko + (((long)b * NKV + w) * SEQ + s) * HD, lane, sa, ca, 1.0f);
  } else if (x < 2 * SEQ) {
    const int id2 = yb * SEQ + (x - SEQ);
    const int s0 = (id2 & 63) * 32;
    const int d0 = ((id2 >> 6) & 3) * 32;
    const int bk = id2 >> 8;           // b*NKV + kvh
    const int b = bk >> 3, kvh = bk & 7;
    const int tx = t & 31, ty = t >> 5;   // 32 x 16
    const u16* src = qkv + ((long)(b * SEQ) + s0) * QKV_N + QSZ + KVSZ + kvh * HD + d0;
    #pragma unroll
    for (int j = 0; j < 32; j += 16)
      tile[ty + j][tx] = src[(long)(ty + j) * QKV_N + tx];
    __syncthreads();
    u16* dst = vt + (((long)bk) * HD + d0) * SEQ + s0;
    #pragma unroll
    for (int j = 0; j < 32; j += 16)
      dst[(long)(ty + j) * SEQ + tx] = tile[tx][ty + j];
  } else {
    const int id3 = yb * 8192 + (x - 2 * SEQ);   // [0, 16384)
    const int bx = id3 & 127, by = id3 >> 7;     // 128 x 128 tiles
    const int c0 = bx << 5, r0 = by << 5;
    const int tx = t & 31, ty = t >> 5;          // 32 x 16
    #pragma unroll
    for (int j = 0; j < 32; j += 16)
      ftile[ty + j][tx] = Wo[(long)(r0 + ty + j) * HIDDEN + c0 + tx];
    __syncthreads();
    #pragma unroll
    for (int j = 0; j < 32; j += 16)
      WoT[(long)(c0 + ty + j) * QSZ + r0 + tx] = f2bf(ftile[tx][ty + j]);
  }
}

// ---------------- stage 3: balanced causal GQA flash attention --------------
// 256 blocks (1/CU) x 512 thr; block (b,h,qp) processes q-tiles {7-qp, qp}:
// causal work = 36 KV-tiles/block, perfectly balanced.
__global__ __launch_bounds__(512, 2)
void flash_attn3(const u16* __restrict__ Qg, const u16* __restrict__ Kg,
                 const u16* __restrict__ Vtg, u16* __restrict__ Og) {
  const int lin = blockIdx.x;          // 256 blocks
  const int b = lin >> 7;
  const int rem = lin & 127;
  const int h = rem >> 2;
  const int qp = rem & 3;
  const int kvh = h >> 2;
  const int t = threadIdx.x, lane = t & 63, w = t >> 6;
  const int hh = lane >> 5, l31 = lane & 31;

  __shared__ u16 Klds[2][64 * 128];   // 2 x 16KB
  __shared__ u16 Vlds[2][128 * 64];   // 2 x 16KB

  const u16* Kbase = Kg + ((long)b * NKV + kvh) * (long)SEQ * HD;   // [kv][128]
  const u16* Vtbase = Vtg + ((long)b * NKV + kvh) * (long)HD * SEQ; // [d][2048]

  auto STAGE = [&](int buf, int kt) {
    const int kv0 = kt * 64;
    #pragma unroll
    for (int i = 0; i < 2; ++i) {   // K: 1024 chunks of 16B
      int c = t + i * 512;
      int kv = c >> 4, cc = c & 15;
      int cl = (cc & 8) | ((cc ^ kv) & 7);      // inverse swizzle on source
      gload_lds16(Kbase + (long)(kv0 + kv) * HD + cl * 8,
                  (char*)(&Klds[buf][0]) + (i * 512 + w * 64) * 16);
    }
    #pragma unroll
    for (int i = 0; i < 2; ++i) {   // V^T: 1024 chunks of 16B
      int c = t + i * 512;
      int d = c >> 3, cc = c & 7;
      int cl = cc ^ (d & 7);
      gload_lds16(Vtbase + (long)d * SEQ + kv0 + cl * 8,
                  (char*)(&Vlds[buf][0]) + (i * 512 + w * 64) * 16);
    }
  };

  for (int seg = 0; seg < 2; ++seg) {
    const int qt = seg ? qp : (7 - qp);   // heavy first
    const int wq0 = qt * 256 + w * 32;
    const int q = wq0 + l31;
    const u16* Qbase = Qg + (((long)b * NH + h) * SEQ + q) * HD + hh * 8;
    bf16x8 qf[8];
    #pragma unroll
    for (int ks = 0; ks < 8; ++ks) qf[ks] = *(const bf16x8*)(Qbase + ks * 16);

    f32x16 o[4];
    #pragma unroll
    for (int i = 0; i < 4; ++i)
      #pragma unroll
      for (int r = 0; r < 16; ++r) o[i][r] = 0.f;
    float m = -1e30f, l = 0.f;
    const int nt = qt * 4 + 4;

    __syncthreads();                 // seg1: all waves done reading seg0's LDS
    STAGE(0, 0);
    __syncthreads();
    int cur = 0;
    for (int kt = 0; kt < nt; ++kt) {
      const int kv0 = kt * 64;
      if (kt + 1 < nt) STAGE(cur ^ 1, kt + 1);
      if (kv0 <= wq0 + 31) {
        const char* Kb = (const char*)(&Klds[cur][0]);
        const char* Vb = (const char*)(&Vlds[cur][0]);
        f32x16 st[2];
        #pragma unroll
        for (int tt = 0; tt < 2; ++tt)
          #pragma unroll
          for (int r = 0; r < 16; ++r) st[tt][r] = 0.f;
        __builtin_amdgcn_s_setprio(1);
        #pragma unroll
        for (int tt = 0; tt < 2; ++tt) {
          if (kv0 + tt * 32 <= wq0 + 31) {
            #pragma unroll
            for (int ks = 0; ks < 8; ++ks) {
              int ch = ks * 2 + hh;
              int pc = (ch & 8) | ((ch ^ l31) & 7);   // swizzled read
              bf16x8 kf = *(const bf16x8*)(Kb + (tt * 32 + l31) * 256 + pc * 16);
              st[tt] = __builtin_amdgcn_mfma_f32_32x32x16_bf16(kf, qf[ks], st[tt], 0, 0, 0);
            }
          }
        }
        __builtin_amdgcn_s_setprio(0);
        if (kv0 + 63 > wq0) {
          #pragma unroll
          for (int tt = 0; tt < 2; ++tt)
            #pragma unroll
            for (int r = 0; r < 16; ++r) {
              int kva = kv0 + tt * 32 + (r & 3) + 8 * (r >> 2) + 4 * hh;
              if (kva > q) st[tt][r] = -1e30f;
            }
        }
        float p0 = -1e30f, p1 = -1e30f, p2 = -1e30f, p3 = -1e30f;
        #pragma unroll
        for (int tt = 0; tt < 2; ++tt)
          #pragma unroll
          for (int r = 0; r < 16; r += 4) {
            p0 = fmaxf(p0, st[tt][r]);
            p1 = fmaxf(p1, st[tt][r + 1]);
            p2 = fmaxf(p2, st[tt][r + 2]);
            p3 = fmaxf(p3, st[tt][r + 3]);
          }
        float mx = fmaxf(fmaxf(p0, p1), fmaxf(p2, p3));
        mx = fmaxf(mx, __shfl_xor(mx, 32));
        if (!__all(mx - m <= THRD)) {            // defer-max (T13)
          float mn = fmaxf(m, mx);
          float sc = exp2f(m - mn);
          m = mn;
          float scr[16];
          #pragma unroll
          for (int r = 0; r < 16; ++r)
            scr[r] = __shfl(sc, (r & 3) + 8 * (r >> 2) + 4 * hh);
          #pragma unroll
          for (int db = 0; db < 4; ++db)
            #pragma unroll
            for (int r = 0; r < 16; ++r) o[db][r] *= scr[r];
          l *= sc;
        }
        float s0 = 0.f, s1 = 0.f, s2 = 0.f, s3 = 0.f;
        #pragma unroll
        for (int tt = 0; tt < 2; ++tt)
          #pragma unroll
          for (int r = 0; r < 16; r += 4) {
            float e0 = exp2f(st[tt][r] - m);
            float e1 = exp2f(st[tt][r + 1] - m);
            float e2 = exp2f(st[tt][r + 2] - m);
            float e3 = exp2f(st[tt][r + 3] - m);
            st[tt][r] = e0; st[tt][r + 1] = e1; st[tt][r + 2] = e2; st[tt][r + 3] = e3;
            s0 += e0; s1 += e1; s2 += e2; s3 += e3;
          }
        float rs = (s0 + s1) + (s2 + s3);
        rs += __shfl_xor(rs, 32);
        l += rs;
        bf16x8 pa[4];
        #pragma unroll
        for (int k4 = 0; k4 < 4; ++k4) {
          int s8 = (k4 & 1) * 8, tt = k4 >> 1;
          u32 x0 = (u32)f2bf(st[tt][s8 + 0]) | ((u32)f2bf(st[tt][s8 + 1]) << 16);
          u32 x1 = (u32)f2bf(st[tt][s8 + 2]) | ((u32)f2bf(st[tt][s8 + 3]) << 16);
          u32 y0 = (u32)f2bf(st[tt][s8 + 4]) | ((u32)f2bf(st[tt][s8 + 5]) << 16);
          u32 y1 = (u32)f2bf(st[tt][s8 + 6]) | ((u32)f2bf(st[tt][s8 + 7]) << 16);
          u32 x0s = (u32)__shfl_xor((int)x0, 32), x1s = (u32)__shfl_xor((int)x1, 32);
          u32 y0s = (u32)__shfl_xor((int)y0, 32), y1s = (u32)__shfl_xor((int)y1, 32);
          union { u32 u[4]; bf16x8 v; } pk;
          pk.u[0] = hh ? y0s : x0;
          pk.u[1] = hh ? y1s : x1;
          pk.u[2] = hh ? y0 : x0s;
          pk.u[3] = hh ? y1 : x1s;
          pa[k4] = pk.v;
        }
        __builtin_amdgcn_s_setprio(1);
        #pragma unroll
        for (int k4 = 0; k4 < 4; ++k4)
          #pragma unroll
          for (int db = 0; db < 4; ++db) {
            int ch = k4 * 2 + hh;
            int pcc = ch ^ (l31 & 7);
            bf16x8 vf = *(const bf16x8*)(Vb + (db * 32 + l31) * 128 + pcc * 16);
            o[db] = __builtin_amdgcn_mfma_f32_32x32x16_bf16(pa[k4], vf, o[db], 0, 0, 0);
          }
        __builtin_amdgcn_s_setprio(0);
      }
      __syncthreads();
      cur ^= 1;
    }
    float linv = 1.0f / l;
    float li[16];
    #pragma unroll
    for (int r = 0; r < 16; ++r)
      li[r] = __shfl(linv, (r & 3) + 8 * (r >> 2) + 4 * hh);
    #pragma unroll
    for (int db = 0; db < 4; ++db)
      #pragma unroll
      for (int r = 0; r < 16; ++r) {
        int qr = wq0 + (r & 3) + 8 * (r >> 2) + 4 * hh;
        Og[((long)b * SEQ + qr) * QSZ + h * HD + db * 32 + l31] = f2bf(o[db][r] * li[r]);
      }
  }
}

// ---------------- launch -----------------------------------------------------
extern "C" void kernel_launch(void* const* d_in, const int* in_sizes, int n_in,
                              void* d_out, int out_size, void* d_ws, size_t ws_size,
                              hipStream_t stream) {
  const int*   positions = (const int*)d_in[0];
  const float* hidden    = (const float*)d_in[1];
  const float* Wqkv      = (const float*)d_in[2];
  const float* qnw       = (const float*)d_in[3];
  const float* knw       = (const float*)d_in[4];
  const float* Wo        = (const float*)d_in[5];
  float* out = (float*)d_out;
  char* ws = (char*)d_ws;
  const size_t MB = 1024 * 1024;
  u16* hbf   = (u16*)(ws + 0);        // 32MB: hidden bf16 (dead after gemm1)
  u16* WqkvT = (u16*)(ws + 32 * MB);  // 48MB: Wqkv^T bf16 (dead after gemm1)
  u16* qkvb  = (u16*)(ws + 80 * MB);  // 48MB: qkv bf16 (dead after ln_rope_v)
  u16* q_arr = (u16*)(ws + 0);        // 32MB (aliases hbf)
  u16* k_arr = (u16*)(ws + 32 * MB);  //  8MB (aliases WqkvT[0:8M])
  u16* vt_arr= (u16*)(ws + 40 * MB);  //  8MB V^T [b][kvh][d][S]
  u16* WoT   = (u16*)(ws + 48 * MB);  // 32MB (aliases WqkvT[16M:48M] -- written
                                      //       only in ln_rope_v, after gemm_bt6)
  u16* Oarr  = (u16*)(ws + 80 * MB);  // 32MB (aliases qkvb[0:32M])

  const int GEMM6_LDS = 3 * 49152;    // 144 KB (QKV GEMM)
  const int GEMM4_LDS = 2 * 65536;    // 128 KB (out GEMM)
  (void)hipFuncSetAttribute((const void*)&gemm_bt6<u16>,
        hipFuncAttributeMaxDynamicSharedMemorySize, GEMM6_LDS);
  (void)hipFuncSetAttribute((const void*)&gemm_bt4<float>,
        hipFuncAttributeMaxDynamicSharedMemorySize, GEMM4_LDS);

  prep_fused<<<dim3(CONV_NBLK + TQKV_NBLK), 256, 0, stream>>>(hidden, hbf, Wqkv, WqkvT);
  gemm_bt6<u16><<<dim3(QKV_N / 256, NTOK / 128), 512, GEMM6_LDS, stream>>>(hbf, WqkvT, qkvb, QKV_N, HIDDEN);
  ln_rope_v<<<dim3(SEQ + SEQ + 8192, NB), 512, 0, stream>>>(
      qkvb, positions, qnw, knw, q_arr, k_arr, vt_arr, Wo, WoT);
  flash_attn3<<<dim3(256), 512, 0, stream>>>(q_arr, k_arr, vt_arr, Oarr);
  gemm_bt4<float><<<dim3(HIDDEN / 256, NTOK / 256), 512, GEMM4_LDS, stream>>>(Oarr, WoT, out, HIDDEN, QSZ);
}